// Round 1
// baseline (217.339 us; speedup 1.0000x reference)
//
#include <hip/hip_runtime.h>
#include <hip/hip_bf16.h>

#define NQ 16384
#define MM 2048
#define DD 128

typedef __attribute__((ext_vector_type(8))) short bf16x8;
typedef __attribute__((ext_vector_type(4))) float f32x4;

#define MFMA16(a, b, c) __builtin_amdgcn_mfma_f32_16x16x32_bf16((a), (b), (c), 0, 0, 0)

static __device__ __forceinline__ unsigned short f2bf(float x) {
    union { __hip_bfloat16 h; unsigned short u; } cv;
    cv.h = __float2bfloat16(x);
    return cv.u;
}
static __device__ __forceinline__ unsigned pk2(float a, float b) {
    return (unsigned)f2bf(a) | ((unsigned)f2bf(b) << 16);
}
static __device__ __forceinline__ bf16x8 ldbf8(const unsigned short* p) {
    return *reinterpret_cast<const bf16x8*>(p);
}

union AW { unsigned u[4]; bf16x8 v; };

// ---------------------------------------------------------------------------
// K0: convert W_t [128x128] and W_t2 [128x256] f32 -> bf16 (row-major kept)
// ---------------------------------------------------------------------------
__global__ void k0_cvt(const float* __restrict__ wt, const float* __restrict__ wt2,
                       unsigned short* __restrict__ wtb, unsigned short* __restrict__ wt2b) {
    int i = blockIdx.x * 256 + threadIdx.x;  // 49152 threads
    if (i < DD * DD) {
        wtb[i] = f2bf(wt[i]);
    } else {
        int j = i - DD * DD;  // < 32768
        wt2b[j] = f2bf(wt2[j]);
    }
}

// ---------------------------------------------------------------------------
// K1: normalize memory_index_w rows -> minn bf16 [M][D];
//     transpose memory_w -> mwt bf16 [D][M]
// block: 256 threads = 64 rows, 4 threads (32 cols) per row. grid: 32
// ---------------------------------------------------------------------------
__global__ __launch_bounds__(256) void k1_prep(const float* __restrict__ miw,
                                               const float* __restrict__ mw,
                                               unsigned short* __restrict__ minn,
                                               unsigned short* __restrict__ mwt) {
    int t = threadIdx.x;
    int m = blockIdx.x * 64 + (t >> 2);
    int q = t & 3;  // column quarter

    const float* rowi = miw + m * DD + q * 32;
    float vi[32];
    float ss = 0.0f;
#pragma unroll
    for (int k = 0; k < 8; ++k) {
        float4 x = reinterpret_cast<const float4*>(rowi)[k];
        vi[4 * k + 0] = x.x; vi[4 * k + 1] = x.y; vi[4 * k + 2] = x.z; vi[4 * k + 3] = x.w;
        ss += x.x * x.x + x.y * x.y + x.z * x.z + x.w * x.w;
    }
    // reduce across the 4-thread quartet (lanes 4m'+q)
    ss += __shfl_xor(ss, 1);
    ss += __shfl_xor(ss, 2);
    float scale = 1.0f / fmaxf(sqrtf(ss), 1e-8f);

    unsigned pk[16];
#pragma unroll
    for (int k = 0; k < 16; ++k) pk[k] = pk2(vi[2 * k] * scale, vi[2 * k + 1] * scale);
    // 64B contiguous store
    unsigned* dst = reinterpret_cast<unsigned*>(minn + m * DD + q * 32);
#pragma unroll
    for (int k = 0; k < 16; ++k) dst[k] = pk[k];

    // memory_w transpose (NOT normalized)
    const float* rowm = mw + m * DD + q * 32;
    float vm[32];
#pragma unroll
    for (int k = 0; k < 8; ++k) {
        float4 x = reinterpret_cast<const float4*>(rowm)[k];
        vm[4 * k + 0] = x.x; vm[4 * k + 1] = x.y; vm[4 * k + 2] = x.z; vm[4 * k + 3] = x.w;
    }
#pragma unroll
    for (int k = 0; k < 32; ++k) mwt[(q * 32 + k) * MM + m] = f2bf(vm[k]);
}

// ---------------------------------------------------------------------------
// K2: tq = query @ W_t^T + b_t; row-normalize; store bf16 [N][D]
// one wave per 16-row strip; 4 waves/block; grid 256
// MFMA 16x16x32: A = query rows (row=lane&15, k=(lane>>4)*8+j),
//                B = W_t rows  (col=lane&15 -> output d, same k layout)
// C/D: col=lane&15 (d), row=4*(lane>>4)+reg (n)   [verified layout]
// ---------------------------------------------------------------------------
__global__ __launch_bounds__(256) void k2_transform(const float* __restrict__ query,
                                                    const unsigned short* __restrict__ wtb,
                                                    const float* __restrict__ bt,
                                                    unsigned short* __restrict__ tqn) {
    int lane = threadIdx.x & 63;
    int wid = threadIdx.x >> 6;
    int nl = lane & 15;
    int g = lane >> 4;
    int n0 = (blockIdx.x * 4 + wid) * 16;

    // A fragments: 4 k-chunks of the query rows, f32 -> bf16
    AW aq[4];
#pragma unroll
    for (int c = 0; c < 4; ++c) {
        const float* p = query + (n0 + nl) * DD + 32 * c + 8 * g;
        float4 x0 = reinterpret_cast<const float4*>(p)[0];
        float4 x1 = reinterpret_cast<const float4*>(p)[1];
        aq[c].u[0] = pk2(x0.x, x0.y); aq[c].u[1] = pk2(x0.z, x0.w);
        aq[c].u[2] = pk2(x1.x, x1.y); aq[c].u[3] = pk2(x1.z, x1.w);
    }

    f32x4 acc[8];
#pragma unroll
    for (int t = 0; t < 8; ++t) acc[t] = (f32x4){0.f, 0.f, 0.f, 0.f};

#pragma unroll
    for (int t = 0; t < 8; ++t) {
#pragma unroll
        for (int c = 0; c < 4; ++c) {
            bf16x8 bv = ldbf8(wtb + (16 * t + nl) * DD + 32 * c + 8 * g);
            acc[t] = MFMA16(aq[c].v, bv, acc[t]);
        }
    }

    // add bias, accumulate squared norms per output row (n = 4g+r)
    float ss[4] = {0.f, 0.f, 0.f, 0.f};
#pragma unroll
    for (int t = 0; t < 8; ++t) {
        float bias = bt[16 * t + nl];
#pragma unroll
        for (int r = 0; r < 4; ++r) {
            float v = acc[t][r] + bias;
            acc[t][r] = v;
            ss[r] += v * v;
        }
    }
#pragma unroll
    for (int r = 0; r < 4; ++r) {
        ss[r] += __shfl_xor(ss[r], 1);
        ss[r] += __shfl_xor(ss[r], 2);
        ss[r] += __shfl_xor(ss[r], 4);
        ss[r] += __shfl_xor(ss[r], 8);
    }
    float scl[4];
#pragma unroll
    for (int r = 0; r < 4; ++r) scl[r] = 1.0f / fmaxf(sqrtf(ss[r]), 1e-8f);

#pragma unroll
    for (int t = 0; t < 8; ++t)
#pragma unroll
        for (int r = 0; r < 4; ++r)
            tqn[(n0 + 4 * g + r) * DD + 16 * t + nl] = f2bf(acc[t][r] * scl[r]);
}

// ---------------------------------------------------------------------------
// K3: fused  exp(tq_n @ mi_n^T) @ memory_w  with denominator accumulation.
// One wave per 16-query strip. Swapped QK^T: S^T[m][n] = mfma(A=Min, B=Qn)
//  -> lane holds n = lane&15 (fixed), m = 4g+r (+16 for 2nd subtile).
// P-transpose to the PV A-fragment (needs m = 8g+j) via 8 shfl + 4 selects.
// ---------------------------------------------------------------------------
__global__ __launch_bounds__(256) void k3_attn(const unsigned short* __restrict__ tqn,
                                               const unsigned short* __restrict__ minn,
                                               const unsigned short* __restrict__ mwt,
                                               float* __restrict__ me_out) {
    int lane = threadIdx.x & 63;
    int wid = threadIdx.x >> 6;
    int nl = lane & 15;
    int g = lane >> 4;
    int n0 = (blockIdx.x * 4 + wid) * 16;

    // persistent Qn B-fragments (col = n, k = d)
    bf16x8 qn[4];
#pragma unroll
    for (int c = 0; c < 4; ++c)
        qn[c] = ldbf8(tqn + (n0 + nl) * DD + 32 * c + 8 * g);

    f32x4 o[8];
#pragma unroll
    for (int t = 0; t < 8; ++t) o[t] = (f32x4){0.f, 0.f, 0.f, 0.f};
    float den = 0.0f;

    const float L2E = 1.44269504088896340736f;
    int src_lo = nl + ((g & 1) ? 32 : 0);
    int src_hi = src_lo + 16;

    for (int it = 0; it < MM / 32; ++it) {
        int m0 = it * 32;
        f32x4 s0 = (f32x4){0.f, 0.f, 0.f, 0.f};
        f32x4 s1 = (f32x4){0.f, 0.f, 0.f, 0.f};
#pragma unroll
        for (int c = 0; c < 4; ++c) {
            bf16x8 a0 = ldbf8(minn + (m0 + nl) * DD + 32 * c + 8 * g);
            bf16x8 a1 = ldbf8(minn + (m0 + 16 + nl) * DD + 32 * c + 8 * g);
            s0 = MFMA16(a0, qn[c], s0);
            s1 = MFMA16(a1, qn[c], s1);
        }
        // exp (cos_sim in [-1,1]: no max subtraction needed)
        float p0[4], p1[4];
#pragma unroll
        for (int r = 0; r < 4; ++r) {
            p0[r] = __builtin_amdgcn_exp2f(s0[r] * L2E);
            p1[r] = __builtin_amdgcn_exp2f(s1[r] * L2E);
            den += p0[r] + p1[r];
        }
        // pack to bf16 pairs
        unsigned q0 = pk2(p0[0], p0[1]);
        unsigned q1 = pk2(p0[2], p0[3]);
        unsigned q2 = pk2(p1[0], p1[1]);
        unsigned q3 = pk2(p1[2], p1[3]);
        // cross-lane exchange: build A-frag P[n=lane&15][m = m0 + 8g + j]
        unsigned b1 = __shfl(q0, src_lo), b2 = __shfl(q2, src_lo);
        unsigned b3 = __shfl(q1, src_lo), b4 = __shfl(q3, src_lo);
        unsigned b5 = __shfl(q0, src_hi), b6 = __shfl(q2, src_hi);
        unsigned b7 = __shfl(q1, src_hi), b8 = __shfl(q3, src_hi);
        AW aw;
        aw.u[0] = (g < 2) ? b1 : b2;
        aw.u[1] = (g < 2) ? b3 : b4;
        aw.u[2] = (g < 2) ? b5 : b6;
        aw.u[3] = (g < 2) ? b7 : b8;
        // PV: O[n][d] += P @ Mw ; B[k=m][col=d] from mwt[d][m] (contiguous)
#pragma unroll
        for (int t = 0; t < 8; ++t) {
            bf16x8 bv = ldbf8(mwt + (16 * t + nl) * MM + m0 + 8 * g);
            o[t] = MFMA16(aw.v, bv, o[t]);
        }
    }

    // complete denominator: sum the 4 g-groups for each n
    den += __shfl_xor(den, 16);
    den += __shfl_xor(den, 32);
    // fetch denominator for output rows n = 4g + r
    float inv[4];
#pragma unroll
    for (int r = 0; r < 4; ++r) inv[r] = 1.0f / __shfl(den, 4 * g + r);

#pragma unroll
    for (int t = 0; t < 8; ++t)
#pragma unroll
        for (int r = 0; r < 4; ++r)
            me_out[(n0 + 4 * g + r) * DD + 16 * t + nl] = o[t][r] * inv[r];
}

// ---------------------------------------------------------------------------
// K4: gating = tanh(cat(mem_emb, query) @ W_t2^T + b_t2);
//     out = query + gating * (mem_emb - query)
// K=256 handled as 8 k-chunks; chunks 0-3 read mem_emb, 4-7 read query.
// ---------------------------------------------------------------------------
__global__ __launch_bounds__(256) void k4_gate(const float* __restrict__ query,
                                               const float* __restrict__ me,
                                               const unsigned short* __restrict__ wt2b,
                                               const float* __restrict__ bt2,
                                               float* __restrict__ out) {
    int lane = threadIdx.x & 63;
    int wid = threadIdx.x >> 6;
    int nl = lane & 15;
    int g = lane >> 4;
    int n0 = (blockIdx.x * 4 + wid) * 16;

    f32x4 acc[8];
#pragma unroll
    for (int t = 0; t < 8; ++t) acc[t] = (f32x4){0.f, 0.f, 0.f, 0.f};

#pragma unroll
    for (int c = 0; c < 8; ++c) {
        int k0 = 32 * c + 8 * g;
        const float* p = (c < 4) ? (me + (n0 + nl) * DD + k0)
                                 : (query + (n0 + nl) * DD + (k0 - DD));
        float4 x0 = reinterpret_cast<const float4*>(p)[0];
        float4 x1 = reinterpret_cast<const float4*>(p)[1];
        AW av;
        av.u[0] = pk2(x0.x, x0.y); av.u[1] = pk2(x0.z, x0.w);
        av.u[2] = pk2(x1.x, x1.y); av.u[3] = pk2(x1.z, x1.w);
#pragma unroll
        for (int t = 0; t < 8; ++t) {
            bf16x8 bv = ldbf8(wt2b + (16 * t + nl) * 256 + k0);
            acc[t] = MFMA16(av.v, bv, acc[t]);
        }
    }

    const float TWO_L2E = 2.88539008177792681472f;  // 2*log2(e)
#pragma unroll
    for (int t = 0; t < 8; ++t) {
        float bias = bt2[16 * t + nl];
        int d = 16 * t + nl;
#pragma unroll
        for (int r = 0; r < 4; ++r) {
            float x = acc[t][r] + bias;
            // tanh(x) = 1 - 2/(exp(2x)+1), stable at both extremes
            float gt = 1.0f - 2.0f / (__builtin_amdgcn_exp2f(x * TWO_L2E) + 1.0f);
            int n = n0 + 4 * g + r;
            float qv = query[n * DD + d];
            float mv = me[n * DD + d];
            out[n * DD + d] = qv + gt * (mv - qv);
        }
    }
}

// ---------------------------------------------------------------------------
extern "C" void kernel_launch(void* const* d_in, const int* in_sizes, int n_in,
                              void* d_out, int out_size, void* d_ws, size_t ws_size,
                              hipStream_t stream) {
    const float* query = (const float*)d_in[0];   // [N,128]
    const float* wt    = (const float*)d_in[1];   // [128,128]
    const float* bt    = (const float*)d_in[2];   // [128]
    const float* miw   = (const float*)d_in[3];   // [M,128]
    const float* mw    = (const float*)d_in[4];   // [M,128]
    const float* wt2   = (const float*)d_in[5];   // [128,256]
    const float* bt2   = (const float*)d_in[6];   // [128]

    float* out    = (float*)d_out;                // output 0: [N,128]
    float* me_out = out + (size_t)NQ * DD;        // output 1: mem_emb [N,128]

    // workspace layout (bf16 arrays), ~5.1 MB total
    unsigned short* tqn  = (unsigned short*)d_ws;          // [N][128]
    unsigned short* minn = tqn + (size_t)NQ * DD;          // [M][128]
    unsigned short* mwt  = minn + (size_t)MM * DD;         // [128][M]
    unsigned short* wtb  = mwt + (size_t)DD * MM;          // [128][128]
    unsigned short* wt2b = wtb + (size_t)DD * DD;          // [128][256]

    k0_cvt<<<(DD * DD + DD * 256 + 255) / 256, 256, 0, stream>>>(wt, wt2, wtb, wt2b);
    k1_prep<<<MM / 64, 256, 0, stream>>>(miw, mw, minn, mwt);
    k2_transform<<<NQ / 64, 256, 0, stream>>>(query, wtb, bt, tqn);
    k3_attn<<<NQ / 64, 256, 0, stream>>>(tqn, minn, mwt, me_out);
    k4_gate<<<NQ / 64, 256, 0, stream>>>(query, me_out, wt2b, bt2, out);
}

// Round 2
// 164.576 us; speedup vs baseline: 1.3206x; 1.3206x over previous
//
#include <hip/hip_runtime.h>
#include <hip/hip_bf16.h>

#define NQ 16384
#define MM 2048
#define DD 128

typedef __attribute__((ext_vector_type(8))) short bf16x8;
typedef __attribute__((ext_vector_type(4))) float f32x4;

#define MFMA16(a, b, c) __builtin_amdgcn_mfma_f32_16x16x32_bf16((a), (b), (c), 0, 0, 0)

static __device__ __forceinline__ unsigned short f2bf(float x) {
    union { __hip_bfloat16 h; unsigned short u; } cv;
    cv.h = __float2bfloat16(x);
    return cv.u;
}
static __device__ __forceinline__ unsigned pk2(float a, float b) {
    return (unsigned)f2bf(a) | ((unsigned)f2bf(b) << 16);
}
static __device__ __forceinline__ bf16x8 ldbf8(const unsigned short* p) {
    return *reinterpret_cast<const bf16x8*>(p);
}

union AW { unsigned u[4]; bf16x8 v; };

// ---------------------------------------------------------------------------
// K0: convert W_t [128x128] and W_t2 [128x256] f32 -> bf16 (row-major kept)
// ---------------------------------------------------------------------------
__global__ void k0_cvt(const float* __restrict__ wt, const float* __restrict__ wt2,
                       unsigned short* __restrict__ wtb, unsigned short* __restrict__ wt2b) {
    int i = blockIdx.x * 256 + threadIdx.x;  // 49152 threads
    if (i < DD * DD) {
        wtb[i] = f2bf(wt[i]);
    } else {
        int j = i - DD * DD;  // < 32768
        wt2b[j] = f2bf(wt2[j]);
    }
}

// ---------------------------------------------------------------------------
// K1: normalize memory_index_w rows -> minn bf16 [M][D];
//     transpose memory_w -> mwt bf16 [D][M]
// ---------------------------------------------------------------------------
__global__ __launch_bounds__(256) void k1_prep(const float* __restrict__ miw,
                                               const float* __restrict__ mw,
                                               unsigned short* __restrict__ minn,
                                               unsigned short* __restrict__ mwt) {
    int t = threadIdx.x;
    int m = blockIdx.x * 64 + (t >> 2);
    int q = t & 3;  // column quarter

    const float* rowi = miw + m * DD + q * 32;
    float vi[32];
    float ss = 0.0f;
#pragma unroll
    for (int k = 0; k < 8; ++k) {
        float4 x = reinterpret_cast<const float4*>(rowi)[k];
        vi[4 * k + 0] = x.x; vi[4 * k + 1] = x.y; vi[4 * k + 2] = x.z; vi[4 * k + 3] = x.w;
        ss += x.x * x.x + x.y * x.y + x.z * x.z + x.w * x.w;
    }
    ss += __shfl_xor(ss, 1);
    ss += __shfl_xor(ss, 2);
    float scale = 1.0f / fmaxf(sqrtf(ss), 1e-8f);

    unsigned pk[16];
#pragma unroll
    for (int k = 0; k < 16; ++k) pk[k] = pk2(vi[2 * k] * scale, vi[2 * k + 1] * scale);
    unsigned* dst = reinterpret_cast<unsigned*>(minn + m * DD + q * 32);
#pragma unroll
    for (int k = 0; k < 16; ++k) dst[k] = pk[k];

    const float* rowm = mw + m * DD + q * 32;
    float vm[32];
#pragma unroll
    for (int k = 0; k < 8; ++k) {
        float4 x = reinterpret_cast<const float4*>(rowm)[k];
        vm[4 * k + 0] = x.x; vm[4 * k + 1] = x.y; vm[4 * k + 2] = x.z; vm[4 * k + 3] = x.w;
    }
#pragma unroll
    for (int k = 0; k < 32; ++k) mwt[(q * 32 + k) * MM + m] = f2bf(vm[k]);
}

// ---------------------------------------------------------------------------
// K2: tq = query @ W_t^T + b_t; row-normalize; store bf16 [N][D]
// ---------------------------------------------------------------------------
__global__ __launch_bounds__(256) void k2_transform(const float* __restrict__ query,
                                                    const unsigned short* __restrict__ wtb,
                                                    const float* __restrict__ bt,
                                                    unsigned short* __restrict__ tqn) {
    int lane = threadIdx.x & 63;
    int wid = threadIdx.x >> 6;
    int nl = lane & 15;
    int g = lane >> 4;
    int n0 = (blockIdx.x * 4 + wid) * 16;

    AW aq[4];
#pragma unroll
    for (int c = 0; c < 4; ++c) {
        const float* p = query + (n0 + nl) * DD + 32 * c + 8 * g;
        float4 x0 = reinterpret_cast<const float4*>(p)[0];
        float4 x1 = reinterpret_cast<const float4*>(p)[1];
        aq[c].u[0] = pk2(x0.x, x0.y); aq[c].u[1] = pk2(x0.z, x0.w);
        aq[c].u[2] = pk2(x1.x, x1.y); aq[c].u[3] = pk2(x1.z, x1.w);
    }

    f32x4 acc[8];
#pragma unroll
    for (int t = 0; t < 8; ++t) acc[t] = (f32x4){0.f, 0.f, 0.f, 0.f};

#pragma unroll
    for (int t = 0; t < 8; ++t) {
#pragma unroll
        for (int c = 0; c < 4; ++c) {
            bf16x8 bv = ldbf8(wtb + (16 * t + nl) * DD + 32 * c + 8 * g);
            acc[t] = MFMA16(aq[c].v, bv, acc[t]);
        }
    }

    float ss[4] = {0.f, 0.f, 0.f, 0.f};
#pragma unroll
    for (int t = 0; t < 8; ++t) {
        float bias = bt[16 * t + nl];
#pragma unroll
        for (int r = 0; r < 4; ++r) {
            float v = acc[t][r] + bias;
            acc[t][r] = v;
            ss[r] += v * v;
        }
    }
#pragma unroll
    for (int r = 0; r < 4; ++r) {
        ss[r] += __shfl_xor(ss[r], 1);
        ss[r] += __shfl_xor(ss[r], 2);
        ss[r] += __shfl_xor(ss[r], 4);
        ss[r] += __shfl_xor(ss[r], 8);
    }
    float scl[4];
#pragma unroll
    for (int r = 0; r < 4; ++r) scl[r] = 1.0f / fmaxf(sqrtf(ss[r]), 1e-8f);

#pragma unroll
    for (int t = 0; t < 8; ++t)
#pragma unroll
        for (int r = 0; r < 4; ++r)
            tqn[(n0 + 4 * g + r) * DD + 16 * t + nl] = f2bf(acc[t][r] * scl[r]);
}

// ---------------------------------------------------------------------------
// K3: fused  exp(tq_n @ mi_n^T) @ memory_w  with denominator accumulation.
// One BLOCK (8 waves, 512 threads) per 16-query strip; wave w covers
// memories [w*256, (w+1)*256). LDS tree reduction combines the 8 partial
// accumulators + denominators; wave 0 normalizes and stores.
// ---------------------------------------------------------------------------
__global__ __launch_bounds__(512) void k3_attn(const unsigned short* __restrict__ tqn,
                                               const unsigned short* __restrict__ minn,
                                               const unsigned short* __restrict__ mwt,
                                               float* __restrict__ me_out) {
    __shared__ float red[4][64][33];  // 33792 B -> 4 blocks/CU
    int lane = threadIdx.x & 63;
    int wid = threadIdx.x >> 6;   // 0..7
    int nl = lane & 15;
    int g = lane >> 4;
    int n0 = blockIdx.x * 16;

    // persistent Qn B-fragments (col = n, k = d) — same for all 8 waves
    bf16x8 qn[4];
#pragma unroll
    for (int c = 0; c < 4; ++c)
        qn[c] = ldbf8(tqn + (n0 + nl) * DD + 32 * c + 8 * g);

    f32x4 o[8];
#pragma unroll
    for (int t = 0; t < 8; ++t) o[t] = (f32x4){0.f, 0.f, 0.f, 0.f};
    float den = 0.0f;

    const float L2E = 1.44269504088896340736f;
    int src_lo = nl + ((g & 1) ? 32 : 0);
    int src_hi = src_lo + 16;

    for (int it = 0; it < 8; ++it) {
        int m0 = wid * 256 + it * 32;
        f32x4 s0 = (f32x4){0.f, 0.f, 0.f, 0.f};
        f32x4 s1 = (f32x4){0.f, 0.f, 0.f, 0.f};
#pragma unroll
        for (int c = 0; c < 4; ++c) {
            bf16x8 a0 = ldbf8(minn + (m0 + nl) * DD + 32 * c + 8 * g);
            bf16x8 a1 = ldbf8(minn + (m0 + 16 + nl) * DD + 32 * c + 8 * g);
            s0 = MFMA16(a0, qn[c], s0);
            s1 = MFMA16(a1, qn[c], s1);
        }
        // exp (cos_sim in [-1,1]: no max subtraction needed)
        float p0[4], p1[4];
#pragma unroll
        for (int r = 0; r < 4; ++r) {
            p0[r] = __builtin_amdgcn_exp2f(s0[r] * L2E);
            p1[r] = __builtin_amdgcn_exp2f(s1[r] * L2E);
            den += p0[r] + p1[r];
        }
        unsigned q0 = pk2(p0[0], p0[1]);
        unsigned q1 = pk2(p0[2], p0[3]);
        unsigned q2 = pk2(p1[0], p1[1]);
        unsigned q3 = pk2(p1[2], p1[3]);
        // cross-lane exchange: build A-frag P[n=lane&15][m = m0 + 8g + j]
        unsigned b1 = __shfl(q0, src_lo), b2 = __shfl(q2, src_lo);
        unsigned b3 = __shfl(q1, src_lo), b4 = __shfl(q3, src_lo);
        unsigned b5 = __shfl(q0, src_hi), b6 = __shfl(q2, src_hi);
        unsigned b7 = __shfl(q1, src_hi), b8 = __shfl(q3, src_hi);
        AW aw;
        aw.u[0] = (g < 2) ? b1 : b2;
        aw.u[1] = (g < 2) ? b3 : b4;
        aw.u[2] = (g < 2) ? b5 : b6;
        aw.u[3] = (g < 2) ? b7 : b8;
        // PV: O[n][d] += P @ Mw ; B[k=m][col=d] from mwt[d][m] (contiguous)
#pragma unroll
        for (int t = 0; t < 8; ++t) {
            bf16x8 bv = ldbf8(mwt + (16 * t + nl) * MM + m0 + 8 * g);
            o[t] = MFMA16(aw.v, bv, o[t]);
        }
    }

    // ---- cross-wave tree reduction in LDS ----
    // Round 1: waves 4..7 -> red[0..3]; waves 0..3 accumulate.
    if (wid >= 4) {
        float* dst = red[wid - 4][lane];
#pragma unroll
        for (int t = 0; t < 8; ++t)
#pragma unroll
            for (int r = 0; r < 4; ++r) dst[4 * t + r] = o[t][r];
        dst[32] = den;
    }
    __syncthreads();
    if (wid < 4) {
        const float* src = red[wid][lane];
#pragma unroll
        for (int t = 0; t < 8; ++t)
#pragma unroll
            for (int r = 0; r < 4; ++r) o[t][r] += src[4 * t + r];
        den += src[32];
    }
    __syncthreads();
    // Round 2: waves 2,3 -> red[0,1]; waves 0,1 accumulate.
    if (wid == 2 || wid == 3) {
        float* dst = red[wid - 2][lane];
#pragma unroll
        for (int t = 0; t < 8; ++t)
#pragma unroll
            for (int r = 0; r < 4; ++r) dst[4 * t + r] = o[t][r];
        dst[32] = den;
    }
    __syncthreads();
    if (wid < 2) {
        const float* src = red[wid][lane];
#pragma unroll
        for (int t = 0; t < 8; ++t)
#pragma unroll
            for (int r = 0; r < 4; ++r) o[t][r] += src[4 * t + r];
        den += src[32];
    }
    __syncthreads();
    // Round 3: wave 1 -> red[0]; wave 0 accumulates + finalizes.
    if (wid == 1) {
        float* dst = red[0][lane];
#pragma unroll
        for (int t = 0; t < 8; ++t)
#pragma unroll
            for (int r = 0; r < 4; ++r) dst[4 * t + r] = o[t][r];
        dst[32] = den;
    }
    __syncthreads();
    if (wid == 0) {
        const float* src = red[0][lane];
#pragma unroll
        for (int t = 0; t < 8; ++t)
#pragma unroll
            for (int r = 0; r < 4; ++r) o[t][r] += src[4 * t + r];
        den += src[32];

        // complete denominator: sum the 4 g-groups for each n
        den += __shfl_xor(den, 16);
        den += __shfl_xor(den, 32);
        float inv[4];
#pragma unroll
        for (int r = 0; r < 4; ++r) inv[r] = 1.0f / __shfl(den, 4 * g + r);

#pragma unroll
        for (int t = 0; t < 8; ++t)
#pragma unroll
            for (int r = 0; r < 4; ++r)
                me_out[(n0 + 4 * g + r) * DD + 16 * t + nl] = o[t][r] * inv[r];
    }
}

// ---------------------------------------------------------------------------
// K4: gating = tanh(cat(mem_emb, query) @ W_t2^T + b_t2);
//     out = query + gating * (mem_emb - query)
// ---------------------------------------------------------------------------
__global__ __launch_bounds__(256) void k4_gate(const float* __restrict__ query,
                                               const float* __restrict__ me,
                                               const unsigned short* __restrict__ wt2b,
                                               const float* __restrict__ bt2,
                                               float* __restrict__ out) {
    int lane = threadIdx.x & 63;
    int wid = threadIdx.x >> 6;
    int nl = lane & 15;
    int g = lane >> 4;
    int n0 = (blockIdx.x * 4 + wid) * 16;

    f32x4 acc[8];
#pragma unroll
    for (int t = 0; t < 8; ++t) acc[t] = (f32x4){0.f, 0.f, 0.f, 0.f};

#pragma unroll
    for (int c = 0; c < 8; ++c) {
        int k0 = 32 * c + 8 * g;
        const float* p = (c < 4) ? (me + (n0 + nl) * DD + k0)
                                 : (query + (n0 + nl) * DD + (k0 - DD));
        float4 x0 = reinterpret_cast<const float4*>(p)[0];
        float4 x1 = reinterpret_cast<const float4*>(p)[1];
        AW av;
        av.u[0] = pk2(x0.x, x0.y); av.u[1] = pk2(x0.z, x0.w);
        av.u[2] = pk2(x1.x, x1.y); av.u[3] = pk2(x1.z, x1.w);
#pragma unroll
        for (int t = 0; t < 8; ++t) {
            bf16x8 bv = ldbf8(wt2b + (16 * t + nl) * 256 + k0);
            acc[t] = MFMA16(av.v, bv, acc[t]);
        }
    }

    const float TWO_L2E = 2.88539008177792681472f;  // 2*log2(e)
#pragma unroll
    for (int t = 0; t < 8; ++t) {
        float bias = bt2[16 * t + nl];
        int d = 16 * t + nl;
#pragma unroll
        for (int r = 0; r < 4; ++r) {
            float x = acc[t][r] + bias;
            float gt = 1.0f - 2.0f / (__builtin_amdgcn_exp2f(x * TWO_L2E) + 1.0f);
            int n = n0 + 4 * g + r;
            float qv = query[n * DD + d];
            float mv = me[n * DD + d];
            out[n * DD + d] = qv + gt * (mv - qv);
        }
    }
}

// ---------------------------------------------------------------------------
extern "C" void kernel_launch(void* const* d_in, const int* in_sizes, int n_in,
                              void* d_out, int out_size, void* d_ws, size_t ws_size,
                              hipStream_t stream) {
    const float* query = (const float*)d_in[0];   // [N,128]
    const float* wt    = (const float*)d_in[1];   // [128,128]
    const float* bt    = (const float*)d_in[2];   // [128]
    const float* miw   = (const float*)d_in[3];   // [M,128]
    const float* mw    = (const float*)d_in[4];   // [M,128]
    const float* wt2   = (const float*)d_in[5];   // [128,256]
    const float* bt2   = (const float*)d_in[6];   // [128]

    float* out    = (float*)d_out;                // output 0: [N,128]
    float* me_out = out + (size_t)NQ * DD;        // output 1: mem_emb [N,128]

    unsigned short* tqn  = (unsigned short*)d_ws;          // [N][128]
    unsigned short* minn = tqn + (size_t)NQ * DD;          // [M][128]
    unsigned short* mwt  = minn + (size_t)MM * DD;         // [128][M]
    unsigned short* wtb  = mwt + (size_t)DD * MM;          // [128][128]
    unsigned short* wt2b = wtb + (size_t)DD * DD;          // [128][256]

    k0_cvt<<<(DD * DD + DD * 256 + 255) / 256, 256, 0, stream>>>(wt, wt2, wtb, wt2b);
    k1_prep<<<MM / 64, 256, 0, stream>>>(miw, mw, minn, mwt);
    k2_transform<<<NQ / 64, 256, 0, stream>>>(query, wtb, bt, tqn);
    k3_attn<<<NQ / 16, 512, 0, stream>>>(tqn, minn, mwt, me_out);
    k4_gate<<<NQ / 64, 256, 0, stream>>>(query, me_out, wt2b, bt2, out);
}

// Round 3
// 107.476 us; speedup vs baseline: 2.0222x; 1.5313x over previous
//
#include <hip/hip_runtime.h>
#include <hip/hip_bf16.h>

#define NQ 16384
#define MM 2048
#define DD 128

typedef __attribute__((ext_vector_type(8))) short bf16x8;
typedef __attribute__((ext_vector_type(4))) float f32x4;

#define MFMA16(a, b, c) __builtin_amdgcn_mfma_f32_16x16x32_bf16((a), (b), (c), 0, 0, 0)

static __device__ __forceinline__ unsigned short f2bf(float x) {
    union { __hip_bfloat16 h; unsigned short u; } cv;
    cv.h = __float2bfloat16(x);
    return cv.u;
}
static __device__ __forceinline__ unsigned pk2(float a, float b) {
    return (unsigned)f2bf(a) | ((unsigned)f2bf(b) << 16);
}
static __device__ __forceinline__ bf16x8 ldbf8(const unsigned short* p) {
    return *reinterpret_cast<const bf16x8*>(p);
}

union AW { unsigned u[4]; bf16x8 v; };

// ---------------------------------------------------------------------------
// K0: convert W_t [128x128] and W_t2 [128x256] f32 -> bf16
// ---------------------------------------------------------------------------
__global__ void k0_cvt(const float* __restrict__ wt, const float* __restrict__ wt2,
                       unsigned short* __restrict__ wtb, unsigned short* __restrict__ wt2b) {
    int i = blockIdx.x * 256 + threadIdx.x;  // 49152 threads
    if (i < DD * DD) {
        wtb[i] = f2bf(wt[i]);
    } else {
        int j = i - DD * DD;  // < 32768
        wt2b[j] = f2bf(wt2[j]);
    }
}

// ---------------------------------------------------------------------------
// K1: normalize memory_index_w rows -> minn bf16 [M][D];
//     transpose memory_w -> mwt bf16 [D][M]
// ---------------------------------------------------------------------------
__global__ __launch_bounds__(256) void k1_prep(const float* __restrict__ miw,
                                               const float* __restrict__ mw,
                                               unsigned short* __restrict__ minn,
                                               unsigned short* __restrict__ mwt) {
    int t = threadIdx.x;
    int m = blockIdx.x * 64 + (t >> 2);
    int q = t & 3;  // column quarter

    const float* rowi = miw + m * DD + q * 32;
    float vi[32];
    float ss = 0.0f;
#pragma unroll
    for (int k = 0; k < 8; ++k) {
        float4 x = reinterpret_cast<const float4*>(rowi)[k];
        vi[4 * k + 0] = x.x; vi[4 * k + 1] = x.y; vi[4 * k + 2] = x.z; vi[4 * k + 3] = x.w;
        ss += x.x * x.x + x.y * x.y + x.z * x.z + x.w * x.w;
    }
    ss += __shfl_xor(ss, 1);
    ss += __shfl_xor(ss, 2);
    float scale = 1.0f / fmaxf(sqrtf(ss), 1e-8f);

    unsigned pk[16];
#pragma unroll
    for (int k = 0; k < 16; ++k) pk[k] = pk2(vi[2 * k] * scale, vi[2 * k + 1] * scale);
    unsigned* dst = reinterpret_cast<unsigned*>(minn + m * DD + q * 32);
#pragma unroll
    for (int k = 0; k < 16; ++k) dst[k] = pk[k];

    const float* rowm = mw + m * DD + q * 32;
    float vm[32];
#pragma unroll
    for (int k = 0; k < 8; ++k) {
        float4 x = reinterpret_cast<const float4*>(rowm)[k];
        vm[4 * k + 0] = x.x; vm[4 * k + 1] = x.y; vm[4 * k + 2] = x.z; vm[4 * k + 3] = x.w;
    }
#pragma unroll
    for (int k = 0; k < 32; ++k) mwt[(q * 32 + k) * MM + m] = f2bf(vm[k]);
}

// ---------------------------------------------------------------------------
// K3 (fused transform + attention):
// Block = 512 thr (8 waves): strip s = wid&3 (16 q each, 64 q/block),
// half h = wid>>2 (m in [h*1024, (h+1)*1024), 32 steps of 32 m).
// Phase 0: h==0 waves compute tq_n for strip s (MFMA vs W_t, bias, norm),
//          store to padded LDS tile; all waves then load Qn B-frags.
// Main loop: minn tiles double-buffered in LDS (272 B padded rows);
//            PV B-frags read direct from global mwt (L1-shared, prefetchable).
// Epilogue: h==1 -> LDS (rotated slots), h==0 merges, normalizes, stores.
// ---------------------------------------------------------------------------
__global__ __launch_bounds__(512, 4) void k3_fused(const float* __restrict__ query,
                                                   const unsigned short* __restrict__ wtb,
                                                   const float* __restrict__ bt,
                                                   const unsigned short* __restrict__ minn,
                                                   const unsigned short* __restrict__ mwt,
                                                   float* __restrict__ me_out) {
    // pool layout:
    //  [0, 17408):   phase-0 tqs tiles, strip s at s*4352, [16 rows][272 B]
    //  [0, 34816):   minn tiles, (h*2+b)*8704, [32 rows][272 B]  (aliases tqs)
    //  [0, 32768):   o-reduction, strip s at s*8192 (after final barrier)
    //  [34816,35840): den reduction float[4][64]
    __shared__ __align__(16) char pool[35840];

    int lane = threadIdx.x & 63;
    int wid = threadIdx.x >> 6;
    int s = wid & 3;
    int h = wid >> 2;
    int nl = lane & 15;
    int g = lane >> 4;
    int n0 = blockIdx.x * 64 + s * 16;

    // ---- Phase 0: transform strip s (h==0 waves only) ----
    if (h == 0) {
        AW aq[4];
#pragma unroll
        for (int c = 0; c < 4; ++c) {
            const float* p = query + (n0 + nl) * DD + 32 * c + 8 * g;
            float4 x0 = reinterpret_cast<const float4*>(p)[0];
            float4 x1 = reinterpret_cast<const float4*>(p)[1];
            aq[c].u[0] = pk2(x0.x, x0.y); aq[c].u[1] = pk2(x0.z, x0.w);
            aq[c].u[2] = pk2(x1.x, x1.y); aq[c].u[3] = pk2(x1.z, x1.w);
        }
        f32x4 acc[8];
#pragma unroll
        for (int t = 0; t < 8; ++t) acc[t] = (f32x4){0.f, 0.f, 0.f, 0.f};
#pragma unroll
        for (int t = 0; t < 8; ++t)
#pragma unroll
            for (int c = 0; c < 4; ++c) {
                bf16x8 bv = ldbf8(wtb + (16 * t + nl) * DD + 32 * c + 8 * g);
                acc[t] = MFMA16(aq[c].v, bv, acc[t]);
            }
        float ss[4] = {0.f, 0.f, 0.f, 0.f};
#pragma unroll
        for (int t = 0; t < 8; ++t) {
            float bias = bt[16 * t + nl];
#pragma unroll
            for (int r = 0; r < 4; ++r) {
                float v = acc[t][r] + bias;
                acc[t][r] = v;
                ss[r] += v * v;
            }
        }
#pragma unroll
        for (int r = 0; r < 4; ++r) {
            ss[r] += __shfl_xor(ss[r], 1);
            ss[r] += __shfl_xor(ss[r], 2);
            ss[r] += __shfl_xor(ss[r], 4);
            ss[r] += __shfl_xor(ss[r], 8);
        }
        float scl[4];
#pragma unroll
        for (int r = 0; r < 4; ++r) scl[r] = 1.0f / fmaxf(sqrtf(ss[r]), 1e-8f);
        // store normalized bf16 to padded tqs tile: (row = 4g+r, col d = 16t+nl)
        char* tq = pool + s * 4352;
#pragma unroll
        for (int t = 0; t < 8; ++t)
#pragma unroll
            for (int r = 0; r < 4; ++r)
                *reinterpret_cast<unsigned short*>(tq + (4 * g + r) * 272 + 2 * (16 * t + nl)) =
                    f2bf(acc[t][r] * scl[r]);
    }
    __syncthreads();

    // all waves: load Qn B-fragments (col=n, k=d) for strip s
    bf16x8 qn[4];
#pragma unroll
    for (int c = 0; c < 4; ++c)
        qn[c] = *reinterpret_cast<const bf16x8*>(pool + s * 4352 + nl * 272 + 64 * c + 16 * g);
    __syncthreads();

    // ---- staging geometry: wave stages rows 8s..8s+7 of its half's tile ----
    int strow = 8 * s + (lane >> 3);      // tile row 0..31
    int stcb = (lane & 7) * 32;           // byte col 0..224

    // prologue: stage tile 0 of this half into buf 0
    {
        const unsigned short* src = minn + ((h * 1024) + strow) * DD + stcb / 2;
        bf16x8 v0 = ldbf8(src);
        bf16x8 v1 = ldbf8(src + 8);
        char* tb = pool + (h * 2 + 0) * 8704;
        *reinterpret_cast<bf16x8*>(tb + strow * 272 + stcb) = v0;
        *reinterpret_cast<bf16x8*>(tb + strow * 272 + stcb + 16) = v1;
    }

    f32x4 o[8];
#pragma unroll
    for (int t = 0; t < 8; ++t) o[t] = (f32x4){0.f, 0.f, 0.f, 0.f};
    float den = 0.0f;

    const float L2E = 1.44269504088896340736f;
    int src_lo = nl + ((g & 1) ? 32 : 0);
    int src_hi = src_lo + 16;

    for (int it = 0; it < 32; ++it) {
        __syncthreads();  // staged tile ready; prior reads of next-buf done
        int cur = it & 1;
        int m0 = h * 1024 + it * 32;
        const char* tb = pool + (h * 2 + cur) * 8704;

        // issue next tile's global loads early (hidden under compute)
        bf16x8 nv0, nv1;
        if (it < 31) {
            const unsigned short* nsrc = minn + (m0 + 32 + strow) * DD + stcb / 2;
            nv0 = ldbf8(nsrc);
            nv1 = ldbf8(nsrc + 8);
        }

        // QK^T from LDS tile (swapped: A = minn rows, B = Qn)
        f32x4 s0 = (f32x4){0.f, 0.f, 0.f, 0.f};
        f32x4 s1 = (f32x4){0.f, 0.f, 0.f, 0.f};
#pragma unroll
        for (int c = 0; c < 4; ++c) {
            bf16x8 a0 = *reinterpret_cast<const bf16x8*>(tb + nl * 272 + 64 * c + 16 * g);
            bf16x8 a1 = *reinterpret_cast<const bf16x8*>(tb + (nl + 16) * 272 + 64 * c + 16 * g);
            s0 = MFMA16(a0, qn[c], s0);
            s1 = MFMA16(a1, qn[c], s1);
        }
        // exp (cos_sim in [-1,1]: no max subtraction needed)
        float p0[4], p1[4];
#pragma unroll
        for (int r = 0; r < 4; ++r) {
            p0[r] = __builtin_amdgcn_exp2f(s0[r] * L2E);
            p1[r] = __builtin_amdgcn_exp2f(s1[r] * L2E);
            den += p0[r] + p1[r];
        }
        unsigned q0 = pk2(p0[0], p0[1]);
        unsigned q1 = pk2(p0[2], p0[3]);
        unsigned q2 = pk2(p1[0], p1[1]);
        unsigned q3 = pk2(p1[2], p1[3]);
        // cross-lane exchange: build A-frag P[n=lane&15][m = m0 + 8g + j]
        unsigned b1 = __shfl(q0, src_lo), b2 = __shfl(q2, src_lo);
        unsigned b3 = __shfl(q1, src_lo), b4 = __shfl(q3, src_lo);
        unsigned b5 = __shfl(q0, src_hi), b6 = __shfl(q2, src_hi);
        unsigned b7 = __shfl(q1, src_hi), b8 = __shfl(q3, src_hi);
        AW aw;
        aw.u[0] = (g < 2) ? b1 : b2;
        aw.u[1] = (g < 2) ? b3 : b4;
        aw.u[2] = (g < 2) ? b5 : b6;
        aw.u[3] = (g < 2) ? b7 : b8;
        // PV: O[n][d] += P @ Mw ; B-frag from global mwt[d][m] (L1-shared)
#pragma unroll
        for (int t = 0; t < 8; ++t) {
            bf16x8 bv = ldbf8(mwt + (16 * t + nl) * MM + m0 + 8 * g);
            o[t] = MFMA16(aw.v, bv, o[t]);
        }

        // write staged regs into next buffer (vmcnt wait lands here, late)
        if (it < 31) {
            char* nb = pool + (h * 2 + (cur ^ 1)) * 8704;
            *reinterpret_cast<bf16x8*>(nb + strow * 272 + stcb) = nv0;
            *reinterpret_cast<bf16x8*>(nb + strow * 272 + stcb + 16) = nv1;
        }
    }

    // ---- cross-half reduction ----
    __syncthreads();
    float* ored = reinterpret_cast<float*>(pool);
    float* dred = reinterpret_cast<float*>(pool + 34816);
    if (h == 1) {
#pragma unroll
        for (int t = 0; t < 8; ++t)
            *reinterpret_cast<f32x4*>(ored + s * 2048 + lane * 32 + ((t + lane) & 7) * 4) = o[t];
        dred[s * 64 + lane] = den;
    }
    __syncthreads();
    if (h == 0) {
#pragma unroll
        for (int t = 0; t < 8; ++t) {
            f32x4 v = *reinterpret_cast<const f32x4*>(ored + s * 2048 + lane * 32 + ((t + lane) & 7) * 4);
#pragma unroll
            for (int r = 0; r < 4; ++r) o[t][r] += v[r];
        }
        den += dred[s * 64 + lane];
        // complete denominator: sum the 4 g-groups for each n
        den += __shfl_xor(den, 16);
        den += __shfl_xor(den, 32);
        float inv[4];
#pragma unroll
        for (int r = 0; r < 4; ++r) inv[r] = 1.0f / __shfl(den, 4 * g + r);
#pragma unroll
        for (int t = 0; t < 8; ++t)
#pragma unroll
            for (int r = 0; r < 4; ++r)
                me_out[(n0 + 4 * g + r) * DD + 16 * t + nl] = o[t][r] * inv[r];
    }
}

// ---------------------------------------------------------------------------
// K4: gating = tanh(cat(mem_emb, query) @ W_t2^T + b_t2);
//     out = query + gating * (mem_emb - query)
// 8 waves: strip s = wid&3, concat-half h = wid>>2 (h=0: me/k<128, h=1: query).
// ---------------------------------------------------------------------------
__global__ __launch_bounds__(512, 4) void k4_gate(const float* __restrict__ query,
                                                  const float* __restrict__ me,
                                                  const unsigned short* __restrict__ wt2b,
                                                  const float* __restrict__ bt2,
                                                  float* __restrict__ out) {
    __shared__ __align__(16) float red[4][64][32];
    int lane = threadIdx.x & 63;
    int wid = threadIdx.x >> 6;
    int s = wid & 3;
    int h = wid >> 2;
    int nl = lane & 15;
    int g = lane >> 4;
    int n0 = blockIdx.x * 64 + s * 16;

    f32x4 acc[8];
#pragma unroll
    for (int t = 0; t < 8; ++t) acc[t] = (f32x4){0.f, 0.f, 0.f, 0.f};

    const float* abase = (h == 0) ? me : query;
#pragma unroll
    for (int c = 0; c < 4; ++c) {
        int k0 = 32 * c + 8 * g;
        const float* p = abase + (n0 + nl) * DD + k0;
        float4 x0 = reinterpret_cast<const float4*>(p)[0];
        float4 x1 = reinterpret_cast<const float4*>(p)[1];
        AW av;
        av.u[0] = pk2(x0.x, x0.y); av.u[1] = pk2(x0.z, x0.w);
        av.u[2] = pk2(x1.x, x1.y); av.u[3] = pk2(x1.z, x1.w);
#pragma unroll
        for (int t = 0; t < 8; ++t) {
            bf16x8 bv = ldbf8(wt2b + (16 * t + nl) * 256 + h * 128 + k0);
            acc[t] = MFMA16(av.v, bv, acc[t]);
        }
    }

    if (h == 1) {
#pragma unroll
        for (int t = 0; t < 8; ++t)
            *reinterpret_cast<f32x4*>(&red[s][lane][((t + lane) & 7) * 4]) = acc[t];
    }
    __syncthreads();
    if (h == 0) {
#pragma unroll
        for (int t = 0; t < 8; ++t) {
            f32x4 v = *reinterpret_cast<const f32x4*>(&red[s][lane][((t + lane) & 7) * 4]);
#pragma unroll
            for (int r = 0; r < 4; ++r) acc[t][r] += v[r];
        }
        const float TWO_L2E = 2.88539008177792681472f;  // 2*log2(e)
#pragma unroll
        for (int t = 0; t < 8; ++t) {
            float bias = bt2[16 * t + nl];
            int d = 16 * t + nl;
#pragma unroll
            for (int r = 0; r < 4; ++r) {
                float x = acc[t][r] + bias;
                float gt = 1.0f - 2.0f / (__builtin_amdgcn_exp2f(x * TWO_L2E) + 1.0f);
                int n = n0 + 4 * g + r;
                float qv = query[n * DD + d];
                float mv = me[n * DD + d];
                out[n * DD + d] = qv + gt * (mv - qv);
            }
        }
    }
}

// ---------------------------------------------------------------------------
extern "C" void kernel_launch(void* const* d_in, const int* in_sizes, int n_in,
                              void* d_out, int out_size, void* d_ws, size_t ws_size,
                              hipStream_t stream) {
    const float* query = (const float*)d_in[0];   // [N,128]
    const float* wt    = (const float*)d_in[1];   // [128,128]
    const float* bt    = (const float*)d_in[2];   // [128]
    const float* miw   = (const float*)d_in[3];   // [M,128]
    const float* mw    = (const float*)d_in[4];   // [M,128]
    const float* wt2   = (const float*)d_in[5];   // [128,256]
    const float* bt2   = (const float*)d_in[6];   // [128]

    float* out    = (float*)d_out;                // output 0: [N,128]
    float* me_out = out + (size_t)NQ * DD;        // output 1: mem_emb [N,128]

    // workspace layout (bf16 arrays), ~1.2 MB total
    unsigned short* minn = (unsigned short*)d_ws;          // [M][128]
    unsigned short* mwt  = minn + (size_t)MM * DD;         // [128][M]
    unsigned short* wtb  = mwt + (size_t)DD * MM;          // [128][128]
    unsigned short* wt2b = wtb + (size_t)DD * DD;          // [128][256]

    k0_cvt<<<(DD * DD + DD * 256 + 255) / 256, 256, 0, stream>>>(wt, wt2, wtb, wt2b);
    k1_prep<<<MM / 64, 256, 0, stream>>>(miw, mw, minn, mwt);
    k3_fused<<<NQ / 64, 512, 0, stream>>>(query, wtb, bt, minn, mwt, me_out);
    k4_gate<<<NQ / 64, 512, 0, stream>>>(query, me_out, wt2b, bt2, out);
}

// Round 4
// 95.070 us; speedup vs baseline: 2.2861x; 1.1305x over previous
//
#include <hip/hip_runtime.h>
#include <hip/hip_bf16.h>

#define NQ 16384
#define MM 2048
#define DD 128

typedef __attribute__((ext_vector_type(8))) short bf16x8;
typedef __attribute__((ext_vector_type(4))) float f32x4;
typedef __attribute__((ext_vector_type(16))) float f32x16;

#define MFMA16(a, b, c) __builtin_amdgcn_mfma_f32_16x16x32_bf16((a), (b), (c), 0, 0, 0)
#define MFMA32(a, b, c) __builtin_amdgcn_mfma_f32_32x32x16_bf16((a), (b), (c), 0, 0, 0)

static __device__ __forceinline__ unsigned short f2bf(float x) {
    union { __hip_bfloat16 h; unsigned short u; } cv;
    cv.h = __float2bfloat16(x);
    return cv.u;
}
static __device__ __forceinline__ unsigned pk2(float a, float b) {
    return (unsigned)f2bf(a) | ((unsigned)f2bf(b) << 16);
}
static __device__ __forceinline__ bf16x8 ldbf8(const unsigned short* p) {
    return *reinterpret_cast<const bf16x8*>(p);
}

union AW { unsigned u[4]; bf16x8 v; };

// ---------------------------------------------------------------------------
// K0: convert W_t [128x128] and W_t2 [128x256] f32 -> bf16
// ---------------------------------------------------------------------------
__global__ void k0_cvt(const float* __restrict__ wt, const float* __restrict__ wt2,
                       unsigned short* __restrict__ wtb, unsigned short* __restrict__ wt2b) {
    int i = blockIdx.x * 256 + threadIdx.x;  // 49152 threads
    if (i < DD * DD) {
        wtb[i] = f2bf(wt[i]);
    } else {
        int j = i - DD * DD;  // < 32768
        wt2b[j] = f2bf(wt2[j]);
    }
}

// ---------------------------------------------------------------------------
// K1: normalize memory_index_w rows -> minn bf16 [M][D];
//     transpose memory_w -> mwt bf16 [D][M]
// ---------------------------------------------------------------------------
__global__ __launch_bounds__(256) void k1_prep(const float* __restrict__ miw,
                                               const float* __restrict__ mw,
                                               unsigned short* __restrict__ minn,
                                               unsigned short* __restrict__ mwt) {
    int t = threadIdx.x;
    int m = blockIdx.x * 64 + (t >> 2);
    int q = t & 3;  // column quarter

    const float* rowi = miw + m * DD + q * 32;
    float vi[32];
    float ss = 0.0f;
#pragma unroll
    for (int k = 0; k < 8; ++k) {
        float4 x = reinterpret_cast<const float4*>(rowi)[k];
        vi[4 * k + 0] = x.x; vi[4 * k + 1] = x.y; vi[4 * k + 2] = x.z; vi[4 * k + 3] = x.w;
        ss += x.x * x.x + x.y * x.y + x.z * x.z + x.w * x.w;
    }
    ss += __shfl_xor(ss, 1);
    ss += __shfl_xor(ss, 2);
    float scale = 1.0f / fmaxf(sqrtf(ss), 1e-8f);

    unsigned pk[16];
#pragma unroll
    for (int k = 0; k < 16; ++k) pk[k] = pk2(vi[2 * k] * scale, vi[2 * k + 1] * scale);
    unsigned* dst = reinterpret_cast<unsigned*>(minn + m * DD + q * 32);
#pragma unroll
    for (int k = 0; k < 16; ++k) dst[k] = pk[k];

    const float* rowm = mw + m * DD + q * 32;
    float vm[32];
#pragma unroll
    for (int k = 0; k < 8; ++k) {
        float4 x = reinterpret_cast<const float4*>(rowm)[k];
        vm[4 * k + 0] = x.x; vm[4 * k + 1] = x.y; vm[4 * k + 2] = x.z; vm[4 * k + 3] = x.w;
    }
#pragma unroll
    for (int k = 0; k < 32; ++k) mwt[(q * 32 + k) * MM + m] = f2bf(vm[k]);
}

// ---------------------------------------------------------------------------
// K3: fused transform + attention, 32x32 MFMA, barrier-free main loop.
// Grid 512 x 256thr (2 blocks/CU). Block = one 32-query strip.
// Wave w (0..3) = m-quarter [w*512, (w+1)*512), 16 iters of 32 m.
// Phase 0: waves 0,1 compute tq_n (x log2e) for 16 q each -> LDS tile.
// Main loop: QK A-frags register-double-buffered from global minn; swapped
//   QK^T (D[m][n]); P-transpose via 8 cvt_pk + 4 permlane32_swap; PV with
//   B-frags from global mwt[d][m]. No LDS, no barriers inside loop.
// Epilogue: waves 1-3 dump partial O+den to LDS, wave 0 reduces + stores.
// ---------------------------------------------------------------------------
__global__ __launch_bounds__(256, 2) void k3_fused(const float* __restrict__ query,
                                                   const unsigned short* __restrict__ wtb,
                                                   const float* __restrict__ bt,
                                                   const unsigned short* __restrict__ minn,
                                                   const unsigned short* __restrict__ mwt,
                                                   float* __restrict__ me_out) {
    __shared__ __align__(16) unsigned short tq[32 * 136];  // 272B rows, 8704 B
    __shared__ __align__(16) float red[3][64 * 68];        // 272B/lane, 52224 B

    const int lane = threadIdx.x & 63;
    const int wid = threadIdx.x >> 6;   // m-quarter
    const int ml = lane & 31;
    const int hi = lane >> 5;
    const int n0 = blockIdx.x * 32;
    const float L2E = 1.44269504088896340736f;

    // ---- Phase 0: transform 32 q of this strip (waves 0,1; 16x16 path) ----
    if (wid < 2) {
        const int nl = lane & 15;
        const int g = lane >> 4;
        const int qb = n0 + 16 * wid;
        AW aq[4];
#pragma unroll
        for (int c = 0; c < 4; ++c) {
            const float* p = query + (qb + nl) * DD + 32 * c + 8 * g;
            float4 x0 = reinterpret_cast<const float4*>(p)[0];
            float4 x1 = reinterpret_cast<const float4*>(p)[1];
            aq[c].u[0] = pk2(x0.x, x0.y); aq[c].u[1] = pk2(x0.z, x0.w);
            aq[c].u[2] = pk2(x1.x, x1.y); aq[c].u[3] = pk2(x1.z, x1.w);
        }
        f32x4 acc[8];
#pragma unroll
        for (int t = 0; t < 8; ++t) acc[t] = (f32x4){0.f, 0.f, 0.f, 0.f};
#pragma unroll
        for (int t = 0; t < 8; ++t)
#pragma unroll
            for (int c = 0; c < 4; ++c) {
                bf16x8 bv = ldbf8(wtb + (16 * t + nl) * DD + 32 * c + 8 * g);
                acc[t] = MFMA16(aq[c].v, bv, acc[t]);
            }
        float ss[4] = {0.f, 0.f, 0.f, 0.f};
#pragma unroll
        for (int t = 0; t < 8; ++t) {
            float bias = bt[16 * t + nl];
#pragma unroll
            for (int r = 0; r < 4; ++r) {
                float v = acc[t][r] + bias;
                acc[t][r] = v;
                ss[r] += v * v;
            }
        }
#pragma unroll
        for (int r = 0; r < 4; ++r) {
            ss[r] += __shfl_xor(ss[r], 1);
            ss[r] += __shfl_xor(ss[r], 2);
            ss[r] += __shfl_xor(ss[r], 4);
            ss[r] += __shfl_xor(ss[r], 8);
        }
        float scl[4];
#pragma unroll
        for (int r = 0; r < 4; ++r) scl[r] = L2E / fmaxf(sqrtf(ss[r]), 1e-8f);
        // rows 16w + 4g + r, col d = 16t + nl  (tq_n pre-scaled by log2(e))
#pragma unroll
        for (int t = 0; t < 8; ++t)
#pragma unroll
            for (int r = 0; r < 4; ++r)
                tq[(16 * wid + 4 * g + r) * 136 + 16 * t + nl] = f2bf(acc[t][r] * scl[r]);
    }
    __syncthreads();

    // Qn B-fragments for 32x32x16: col n = ml, k(d-chunk c) = 8*hi + j
    bf16x8 qn[8];
#pragma unroll
    for (int c = 0; c < 8; ++c)
        qn[c] = *reinterpret_cast<const bf16x8*>(&tq[ml * 136 + 16 * c + 8 * hi]);

    const f32x16 zero16 = {0.f,0.f,0.f,0.f,0.f,0.f,0.f,0.f,0.f,0.f,0.f,0.f,0.f,0.f,0.f,0.f};
    f32x16 o[4];
#pragma unroll
    for (int t = 0; t < 4; ++t) o[t] = zero16;
    float den = 0.0f;

    const int mbase = wid * 512;

    // A-frag double buffer: row m = mbase + it*32 + ml, k(chunk c) d = 16c+8hi+j
    bf16x8 aA[2][8];
#pragma unroll
    for (int c = 0; c < 8; ++c)
        aA[0][c] = ldbf8(minn + (mbase + ml) * DD + 16 * c + 8 * hi);

#pragma unroll 2
    for (int it = 0; it < 16; ++it) {
        const int cur = it & 1;
        const int m0 = mbase + it * 32;
        // prefetch next iteration's A-frags (full iteration of latency cover)
        if (it < 15) {
#pragma unroll
            for (int c = 0; c < 8; ++c)
                aA[cur ^ 1][c] = ldbf8(minn + (m0 + 32 + ml) * DD + 16 * c + 8 * hi);
        }
        // QK^T: D[m][n], two 4-deep accumulate chains over d
        f32x16 sA = zero16, sB = zero16;
#pragma unroll
        for (int c = 0; c < 4; ++c) sA = MFMA32(aA[cur][c], qn[c], sA);
#pragma unroll
        for (int c = 4; c < 8; ++c) sB = MFMA32(aA[cur][c], qn[c], sB);
        // PV B-frags: col d = 32dt + ml, k = m0 + 16kc + 8hi + j
        bf16x8 bw[8];
#pragma unroll
        for (int dt = 0; dt < 4; ++dt)
#pragma unroll
            for (int kc = 0; kc < 2; ++kc)
                bw[dt * 2 + kc] = ldbf8(mwt + (32 * dt + ml) * MM + m0 + 16 * kc + 8 * hi);
        // numerators: p = exp2(cos*log2e)  (cos in [-1,1]: no max needed)
        float p[16];
#pragma unroll
        for (int r = 0; r < 16; ++r)
            p[r] = __builtin_amdgcn_exp2f(sA[r] + sB[r]);
        {
            float d0 = (p[0] + p[1]) + (p[2] + p[3]);
            float d1 = (p[4] + p[5]) + (p[6] + p[7]);
            float d2 = (p[8] + p[9]) + (p[10] + p[11]);
            float d3 = (p[12] + p[13]) + (p[14] + p[15]);
            den += (d0 + d1) + (d2 + d3);
        }
        // pack and cross-half exchange -> PV A-frags
        // C-reg r holds m = (r&3) + 8*(r>>2) + 4*hi; w[j] = (p[2j], p[2j+1])
        unsigned w0 = pk2(p[0], p[1]),  w1 = pk2(p[2], p[3]);
        unsigned w2 = pk2(p[4], p[5]),  w3 = pk2(p[6], p[7]);
        unsigned w4 = pk2(p[8], p[9]),  w5 = pk2(p[10], p[11]);
        unsigned w6 = pk2(p[12], p[13]), w7 = pk2(p[14], p[15]);
        auto r02 = __builtin_amdgcn_permlane32_swap(w0, w2, false, false);
        auto r13 = __builtin_amdgcn_permlane32_swap(w1, w3, false, false);
        auto r46 = __builtin_amdgcn_permlane32_swap(w4, w6, false, false);
        auto r57 = __builtin_amdgcn_permlane32_swap(w5, w7, false, false);
        AW a0, a1;
        a0.u[0] = r02[0]; a0.u[1] = r13[0]; a0.u[2] = r02[1]; a0.u[3] = r13[1];
        a1.u[0] = r46[0]; a1.u[1] = r57[0]; a1.u[2] = r46[1]; a1.u[3] = r57[1];
        // PV: O[n][d] += P @ Mw
#pragma unroll
        for (int dt = 0; dt < 4; ++dt) {
            o[dt] = MFMA32(a0.v, bw[dt * 2 + 0], o[dt]);
            o[dt] = MFMA32(a1.v, bw[dt * 2 + 1], o[dt]);
        }
    }

    // ---- cross-wave reduction: waves 1-3 dump, wave 0 combines ----
    if (wid > 0) {
        float* dst = &red[wid - 1][lane * 68];
#pragma unroll
        for (int t = 0; t < 4; ++t)
#pragma unroll
            for (int k = 0; k < 4; ++k) {
                f32x4 v = {o[t][4 * k + 0], o[t][4 * k + 1], o[t][4 * k + 2], o[t][4 * k + 3]};
                *reinterpret_cast<f32x4*>(dst + 16 * t + 4 * k) = v;
            }
        dst[64] = den;
    }
    __syncthreads();
    if (wid == 0) {
        for (int s = 0; s < 3; ++s) {
            const float* src = &red[s][lane * 68];
#pragma unroll
            for (int t = 0; t < 4; ++t)
#pragma unroll
                for (int k = 0; k < 4; ++k) {
                    f32x4 v = *reinterpret_cast<const f32x4*>(src + 16 * t + 4 * k);
                    o[t][4 * k + 0] += v[0]; o[t][4 * k + 1] += v[1];
                    o[t][4 * k + 2] += v[2]; o[t][4 * k + 3] += v[3];
                }
            den += src[64];
        }
        // den per n=ml is split across lane halves (m offset +4): combine
        den += __shfl_xor(den, 32);
        float invd = 1.0f / den;
        float inv[16];
#pragma unroll
        for (int r = 0; r < 16; ++r)
            inv[r] = __shfl(invd, (r & 3) + 8 * (r >> 2) + 4 * hi);
#pragma unroll
        for (int t = 0; t < 4; ++t)
#pragma unroll
            for (int r = 0; r < 16; ++r)
                me_out[(n0 + (r & 3) + 8 * (r >> 2) + 4 * hi) * DD + 32 * t + ml] =
                    o[t][r] * inv[r];
    }
}

// ---------------------------------------------------------------------------
// K4: gating = tanh(cat(mem_emb, query) @ W_t2^T + b_t2);
//     out = query + gating * (mem_emb - query)
// 256 thr: strip s = wid&1 (16 q), concat-half h = wid>>1. Grid = NQ/32.
// ---------------------------------------------------------------------------
__global__ __launch_bounds__(256) void k4_gate(const float* __restrict__ query,
                                               const float* __restrict__ me,
                                               const unsigned short* __restrict__ wt2b,
                                               const float* __restrict__ bt2,
                                               float* __restrict__ out) {
    __shared__ __align__(16) float red[2][64][32];
    int lane = threadIdx.x & 63;
    int wid = threadIdx.x >> 6;
    int s = wid & 1;
    int h = wid >> 1;
    int nl = lane & 15;
    int g = lane >> 4;
    int n0 = blockIdx.x * 32 + s * 16;

    f32x4 acc[8];
#pragma unroll
    for (int t = 0; t < 8; ++t) acc[t] = (f32x4){0.f, 0.f, 0.f, 0.f};

    const float* abase = (h == 0) ? me : query;
#pragma unroll
    for (int c = 0; c < 4; ++c) {
        int k0 = 32 * c + 8 * g;
        const float* p = abase + (n0 + nl) * DD + k0;
        float4 x0 = reinterpret_cast<const float4*>(p)[0];
        float4 x1 = reinterpret_cast<const float4*>(p)[1];
        AW av;
        av.u[0] = pk2(x0.x, x0.y); av.u[1] = pk2(x0.z, x0.w);
        av.u[2] = pk2(x1.x, x1.y); av.u[3] = pk2(x1.z, x1.w);
#pragma unroll
        for (int t = 0; t < 8; ++t) {
            bf16x8 bv = ldbf8(wt2b + (16 * t + nl) * 256 + h * 128 + k0);
            acc[t] = MFMA16(av.v, bv, acc[t]);
        }
    }

    if (h == 1) {
#pragma unroll
        for (int t = 0; t < 8; ++t)
            *reinterpret_cast<f32x4*>(&red[s][lane][((t + lane) & 7) * 4]) = acc[t];
    }
    __syncthreads();
    if (h == 0) {
#pragma unroll
        for (int t = 0; t < 8; ++t) {
            f32x4 v = *reinterpret_cast<const f32x4*>(&red[s][lane][((t + lane) & 7) * 4]);
#pragma unroll
            for (int r = 0; r < 4; ++r) acc[t][r] += v[r];
        }
        const float TWO_L2E = 2.88539008177792681472f;  // 2*log2(e)
#pragma unroll
        for (int t = 0; t < 8; ++t) {
            float bias = bt2[16 * t + nl];
            int d = 16 * t + nl;
#pragma unroll
            for (int r = 0; r < 4; ++r) {
                float x = acc[t][r] + bias;
                float gt = 1.0f - 2.0f / (__builtin_amdgcn_exp2f(x * TWO_L2E) + 1.0f);
                int n = n0 + 4 * g + r;
                float qv = query[n * DD + d];
                float mv = me[n * DD + d];
                out[n * DD + d] = qv + gt * (mv - qv);
            }
        }
    }
}

// ---------------------------------------------------------------------------
extern "C" void kernel_launch(void* const* d_in, const int* in_sizes, int n_in,
                              void* d_out, int out_size, void* d_ws, size_t ws_size,
                              hipStream_t stream) {
    const float* query = (const float*)d_in[0];   // [N,128]
    const float* wt    = (const float*)d_in[1];   // [128,128]
    const float* bt    = (const float*)d_in[2];   // [128]
    const float* miw   = (const float*)d_in[3];   // [M,128]
    const float* mw    = (const float*)d_in[4];   // [M,128]
    const float* wt2   = (const float*)d_in[5];   // [128,256]
    const float* bt2   = (const float*)d_in[6];   // [128]

    float* out    = (float*)d_out;                // output 0: [N,128]
    float* me_out = out + (size_t)NQ * DD;        // output 1: mem_emb [N,128]

    // workspace layout (bf16 arrays), ~1.2 MB total
    unsigned short* minn = (unsigned short*)d_ws;          // [M][128]
    unsigned short* mwt  = minn + (size_t)MM * DD;         // [128][M]
    unsigned short* wtb  = mwt + (size_t)DD * MM;          // [128][128]
    unsigned short* wt2b = wtb + (size_t)DD * DD;          // [128][256]

    k0_cvt<<<(DD * DD + DD * 256 + 255) / 256, 256, 0, stream>>>(wt, wt2, wtb, wt2b);
    k1_prep<<<MM / 64, 256, 0, stream>>>(miw, mw, minn, mwt);
    k3_fused<<<NQ / 32, 256, 0, stream>>>(query, wtb, bt, minn, mwt, me_out);
    k4_gate<<<NQ / 32, 256, 0, stream>>>(query, me_out, wt2b, bt2, out);
}

// Round 5
// 68.968 us; speedup vs baseline: 3.1513x; 1.3785x over previous
//
#include <hip/hip_runtime.h>
#include <hip/hip_bf16.h>

#define NQ 16384
#define MM 2048
#define DD 128

typedef __attribute__((ext_vector_type(8))) short bf16x8;
typedef __attribute__((ext_vector_type(4))) float f32x4;
typedef __attribute__((ext_vector_type(16))) float f32x16;

#define MFMA16(a, b, c) __builtin_amdgcn_mfma_f32_16x16x32_bf16((a), (b), (c), 0, 0, 0)
#define MFMA32(a, b, c) __builtin_amdgcn_mfma_f32_32x32x16_bf16((a), (b), (c), 0, 0, 0)

static __device__ __forceinline__ unsigned short f2bf(float x) {
    union { __hip_bfloat16 h; unsigned short u; } cv;
    cv.h = __float2bfloat16(x);
    return cv.u;
}
static __device__ __forceinline__ unsigned pk2(float a, float b) {
    return (unsigned)f2bf(a) | ((unsigned)f2bf(b) << 16);
}
static __device__ __forceinline__ float bfl(unsigned u) {
    union { unsigned v; float f; } c; c.v = u << 16; return c.f;
}
static __device__ __forceinline__ float bfh(unsigned u) {
    union { unsigned v; float f; } c; c.v = u & 0xffff0000u; return c.f;
}
static __device__ __forceinline__ bf16x8 ldbf8(const unsigned short* p) {
    return *reinterpret_cast<const bf16x8*>(p);
}

union AW { unsigned u[4]; bf16x8 v; };

// ---------------------------------------------------------------------------
// K01: merged prep.  blocks 0..63: normalize memory_index_w -> minn bf16,
// transpose memory_w -> mwt bf16 [D][M] (32 rows/block, 8 thr/row).
// blocks 64..255: convert W_t / W_t2 -> bf16.
// ---------------------------------------------------------------------------
__global__ __launch_bounds__(256) void k01_prep(const float* __restrict__ miw,
                                                const float* __restrict__ mw,
                                                const float* __restrict__ wt,
                                                const float* __restrict__ wt2,
                                                unsigned short* __restrict__ minn,
                                                unsigned short* __restrict__ mwt,
                                                unsigned short* __restrict__ wtb,
                                                unsigned short* __restrict__ wt2b) {
    int b = blockIdx.x;
    if (b >= 64) {
        int i = (b - 64) * 256 + threadIdx.x;  // 49152 threads
        if (i < DD * DD) wtb[i] = f2bf(wt[i]);
        else             wt2b[i - DD * DD] = f2bf(wt2[i - DD * DD]);
        return;
    }
    int t = threadIdx.x;
    int m = b * 32 + (t >> 3);
    int e = t & 7;  // column eighth (16 cols)

    const float* rowi = miw + m * DD + e * 16;
    float vi[16];
    float ss = 0.0f;
#pragma unroll
    for (int k = 0; k < 4; ++k) {
        float4 x = reinterpret_cast<const float4*>(rowi)[k];
        vi[4 * k + 0] = x.x; vi[4 * k + 1] = x.y; vi[4 * k + 2] = x.z; vi[4 * k + 3] = x.w;
        ss += x.x * x.x + x.y * x.y + x.z * x.z + x.w * x.w;
    }
    ss += __shfl_xor(ss, 1);
    ss += __shfl_xor(ss, 2);
    ss += __shfl_xor(ss, 4);
    float scale = 1.0f / fmaxf(sqrtf(ss), 1e-8f);

    unsigned* dst = reinterpret_cast<unsigned*>(minn + m * DD + e * 16);
#pragma unroll
    for (int k = 0; k < 8; ++k) dst[k] = pk2(vi[2 * k] * scale, vi[2 * k + 1] * scale);

    const float* rowm = mw + m * DD + e * 16;
    float vm[16];
#pragma unroll
    for (int k = 0; k < 4; ++k) {
        float4 x = reinterpret_cast<const float4*>(rowm)[k];
        vm[4 * k + 0] = x.x; vm[4 * k + 1] = x.y; vm[4 * k + 2] = x.z; vm[4 * k + 3] = x.w;
    }
#pragma unroll
    for (int k = 0; k < 16; ++k) mwt[(e * 16 + k) * MM + m] = f2bf(vm[k]);
}

// ---------------------------------------------------------------------------
// K3: fully fused transform + attention + gating.
// Grid 512 x 256thr. Block = one 32-query strip; waves = m-quarters of each
// 128-m iteration tile (16 iters).  minn tiles staged to LDS via
// global_load_lds (double-buffered, source-address XOR-swizzled), raw
// s_barrier + counted vmcnt keeps the next tile's DMA in flight.
// Epilogue: bf16 LDS reduction across waves, then fused gating GEMM.
// ---------------------------------------------------------------------------
__global__ __launch_bounds__(256, 2) void k3_fused(const float* __restrict__ query,
                                                   const unsigned short* __restrict__ wtb,
                                                   const float* __restrict__ bt,
                                                   const unsigned short* __restrict__ minn,
                                                   const unsigned short* __restrict__ mwt,
                                                   const unsigned short* __restrict__ wt2b,
                                                   const float* __restrict__ bt2,
                                                   float* __restrict__ me_out,
                                                   float* __restrict__ out) {
    // pool: [0,32768) bufA (minn tile / epilogue cred slots)
    //       [32768,65536) bufB (minn tile / tq + me LDS tile in first 8704 B)
    __shared__ __align__(16) char pool[65536];
    char* bufA = pool;
    char* bufB = pool + 32768;
    unsigned short* tqm = reinterpret_cast<unsigned short*>(bufB);  // 32 x 136 shorts

    const int lane = threadIdx.x & 63;
    const int wid = threadIdx.x >> 6;   // m-quarter within tile
    const int ml = lane & 31;
    const int hi = lane >> 5;
    const int n0 = blockIdx.x * 32;
    const float L2E = 1.44269504088896340736f;

    // stage one 128x128 bf16 minn tile (32 KB) into buf via global_load_lds.
    // LDS dest linear; global source column XOR-swizzled by (row&15)<<4 so
    // that swizzled ds_read_b128 is bank-conflict-free.
    auto stage_tile = [&](int t0, char* buf) {
#pragma unroll
        for (int k = 0; k < 8; ++k) {
            int seg = wid * 8 + k;                    // 1 KB segment index
            int row = seg * 4 + (lane >> 4);          // tile row this lane hits
            int colb = (lane & 15) * 16;              // dest col byte
            int scol = colb ^ ((row & 15) << 4);      // swizzled source col
            const unsigned short* src = minn + (t0 + row) * DD + scol / 2;
            __builtin_amdgcn_global_load_lds(
                (const __attribute__((address_space(1))) unsigned int*)src,
                (__attribute__((address_space(3))) unsigned int*)(buf + seg * 1024),
                16, 0, 0);
        }
    };

    // prologue: start DMA of tile 0 (lands under phase-0 compute)
    stage_tile(0, bufA);

    // ---- Phase 0: transform 32 q (waves 0,1; 16x16 path), tq pre-scaled L2E
    if (wid < 2) {
        const int nl = lane & 15;
        const int g = lane >> 4;
        const int qb = n0 + 16 * wid;
        AW aq[4];
#pragma unroll
        for (int c = 0; c < 4; ++c) {
            const float* p = query + (qb + nl) * DD + 32 * c + 8 * g;
            float4 x0 = reinterpret_cast<const float4*>(p)[0];
            float4 x1 = reinterpret_cast<const float4*>(p)[1];
            aq[c].u[0] = pk2(x0.x, x0.y); aq[c].u[1] = pk2(x0.z, x0.w);
            aq[c].u[2] = pk2(x1.x, x1.y); aq[c].u[3] = pk2(x1.z, x1.w);
        }
        f32x4 acc[8];
#pragma unroll
        for (int t = 0; t < 8; ++t) acc[t] = (f32x4){0.f, 0.f, 0.f, 0.f};
#pragma unroll
        for (int t = 0; t < 8; ++t)
#pragma unroll
            for (int c = 0; c < 4; ++c) {
                bf16x8 bv = ldbf8(wtb + (16 * t + nl) * DD + 32 * c + 8 * g);
                acc[t] = MFMA16(aq[c].v, bv, acc[t]);
            }
        float ss[4] = {0.f, 0.f, 0.f, 0.f};
#pragma unroll
        for (int t = 0; t < 8; ++t) {
            float bias = bt[16 * t + nl];
#pragma unroll
            for (int r = 0; r < 4; ++r) {
                float v = acc[t][r] + bias;
                acc[t][r] = v;
                ss[r] += v * v;
            }
        }
#pragma unroll
        for (int r = 0; r < 4; ++r) {
            ss[r] += __shfl_xor(ss[r], 1);
            ss[r] += __shfl_xor(ss[r], 2);
            ss[r] += __shfl_xor(ss[r], 4);
            ss[r] += __shfl_xor(ss[r], 8);
        }
        float scl[4];
#pragma unroll
        for (int r = 0; r < 4; ++r) scl[r] = L2E / fmaxf(sqrtf(ss[r]), 1e-8f);
#pragma unroll
        for (int t = 0; t < 8; ++t)
#pragma unroll
            for (int r = 0; r < 4; ++r)
                tqm[(16 * wid + 4 * g + r) * 136 + 16 * t + nl] = f2bf(acc[t][r] * scl[r]);
    }
    __syncthreads();  // full drain: tq visible, tile0 DMA complete

    // Qn B-fragments (col n = ml, k = d)
    bf16x8 qn[8];
#pragma unroll
    for (int c = 0; c < 8; ++c)
        qn[c] = *reinterpret_cast<const bf16x8*>(&tqm[ml * 136 + 16 * c + 8 * hi]);
    __syncthreads();  // qn reads complete before bufB gets DMA'd

    const f32x16 zero16 = {0.f,0.f,0.f,0.f,0.f,0.f,0.f,0.f,0.f,0.f,0.f,0.f,0.f,0.f,0.f,0.f};
    f32x16 o[4];
#pragma unroll
    for (int t = 0; t < 4; ++t) o[t] = zero16;
    float den = 0.0f;

    const int arow_off = 32 * wid + ml;   // this lane's tile row for QK A-frags

#pragma unroll 2
    for (int it = 0; it < 16; ++it) {
        char* cbuf = (it & 1) ? bufB : bufA;
        char* nbuf = (it & 1) ? bufA : bufB;
        if (it < 15) stage_tile((it + 1) * 128, nbuf);
        asm volatile("s_waitcnt vmcnt(8)" ::: "memory");
        __builtin_amdgcn_sched_barrier(0);
        __builtin_amdgcn_s_barrier();          // tile `it` ready in cbuf
        __builtin_amdgcn_sched_barrier(0);

        // QK A-frags from swizzled LDS tile
        const char* arow = cbuf + arow_off * 256;
        bf16x8 aA[8];
#pragma unroll
        for (int c = 0; c < 8; ++c)
            aA[c] = *reinterpret_cast<const bf16x8*>(
                arow + ((32 * c + 16 * hi) ^ ((ml & 15) << 4)));

        f32x16 sA = zero16, sB = zero16;
#pragma unroll
        for (int c = 0; c < 4; ++c) sA = MFMA32(aA[c], qn[c], sA);
#pragma unroll
        for (int c = 4; c < 8; ++c) sB = MFMA32(aA[c], qn[c], sB);

        // PV B-frags direct from global mwt[d][m]
        const int m0 = it * 128 + 32 * wid;
        bf16x8 bw[8];
#pragma unroll
        for (int dt = 0; dt < 4; ++dt)
#pragma unroll
            for (int kc = 0; kc < 2; ++kc)
                bw[dt * 2 + kc] = ldbf8(mwt + (32 * dt + ml) * MM + m0 + 16 * kc + 8 * hi);

        float p[16];
#pragma unroll
        for (int r = 0; r < 16; ++r)
            p[r] = __builtin_amdgcn_exp2f(sA[r] + sB[r]);
        {
            float d0 = (p[0] + p[1]) + (p[2] + p[3]);
            float d1 = (p[4] + p[5]) + (p[6] + p[7]);
            float d2 = (p[8] + p[9]) + (p[10] + p[11]);
            float d3 = (p[12] + p[13]) + (p[14] + p[15]);
            den += (d0 + d1) + (d2 + d3);
        }
        unsigned w0 = pk2(p[0], p[1]),   w1 = pk2(p[2], p[3]);
        unsigned w2 = pk2(p[4], p[5]),   w3 = pk2(p[6], p[7]);
        unsigned w4 = pk2(p[8], p[9]),   w5 = pk2(p[10], p[11]);
        unsigned w6 = pk2(p[12], p[13]), w7 = pk2(p[14], p[15]);
        auto r02 = __builtin_amdgcn_permlane32_swap(w0, w2, false, false);
        auto r13 = __builtin_amdgcn_permlane32_swap(w1, w3, false, false);
        auto r46 = __builtin_amdgcn_permlane32_swap(w4, w6, false, false);
        auto r57 = __builtin_amdgcn_permlane32_swap(w5, w7, false, false);
        AW a0, a1;
        a0.u[0] = r02[0]; a0.u[1] = r13[0]; a0.u[2] = r02[1]; a0.u[3] = r13[1];
        a1.u[0] = r46[0]; a1.u[1] = r57[0]; a1.u[2] = r46[1]; a1.u[3] = r57[1];
#pragma unroll
        for (int dt = 0; dt < 4; ++dt) {
            o[dt] = MFMA32(a0.v, bw[dt * 2 + 0], o[dt]);
            o[dt] = MFMA32(a1.v, bw[dt * 2 + 1], o[dt]);
        }
        __builtin_amdgcn_sched_barrier(0);
        __builtin_amdgcn_s_barrier();          // all reads of cbuf done
        __builtin_amdgcn_sched_barrier(0);
    }

    // ---- cross-wave reduction (bf16 partials in bufA) ----
    if (wid >= 1) {
        char* dst = bufA + (wid - 1) * 8704 + lane * 136;
#pragma unroll
        for (int t = 0; t < 4; ++t) {
            unsigned u[8];
#pragma unroll
            for (int k = 0; k < 8; ++k) u[k] = pk2(o[t][2 * k], o[t][2 * k + 1]);
            *reinterpret_cast<uint4*>(dst + t * 32) = make_uint4(u[0], u[1], u[2], u[3]);
            *reinterpret_cast<uint4*>(dst + t * 32 + 16) = make_uint4(u[4], u[5], u[6], u[7]);
        }
        *reinterpret_cast<float*>(dst + 128) = den;
    }
    __syncthreads();
    if (wid == 0) {
        for (int s = 0; s < 3; ++s) {
            const char* src = bufA + s * 8704 + lane * 136;
#pragma unroll
            for (int t = 0; t < 4; ++t) {
                uint4 ua = *reinterpret_cast<const uint4*>(src + t * 32);
                uint4 ub = *reinterpret_cast<const uint4*>(src + t * 32 + 16);
                unsigned u[8] = {ua.x, ua.y, ua.z, ua.w, ub.x, ub.y, ub.z, ub.w};
#pragma unroll
                for (int k = 0; k < 8; ++k) {
                    o[t][2 * k] += bfl(u[k]);
                    o[t][2 * k + 1] += bfh(u[k]);
                }
            }
            den += *reinterpret_cast<const float*>(src + 128);
        }
        den += __shfl_xor(den, 32);
        float invd = 1.0f / den;
        float inv[16];
#pragma unroll
        for (int r = 0; r < 16; ++r)
            inv[r] = __shfl(invd, (r & 3) + 8 * (r >> 2) + 4 * hi);
#pragma unroll
        for (int t = 0; t < 4; ++t)
#pragma unroll
            for (int r = 0; r < 16; ++r) {
                int row = (r & 3) + 8 * (r >> 2) + 4 * hi;
                float me = o[t][r] * inv[r];
                me_out[(n0 + row) * DD + 32 * t + ml] = me;
                tqm[row * 136 + 32 * t + ml] = f2bf(me);  // me tile for gating
            }
    }
    __syncthreads();

    // ---- fused gating: G = tanh(cat(me,q) @ W_t2^T + b_t2); blend ----
    {
        const int dt = wid;  // d-tile 32*dt .. 32*dt+31
        f32x16 g = zero16;
#pragma unroll
        for (int c = 0; c < 8; ++c) {  // k < 128: me from LDS tile
            bf16x8 av = *reinterpret_cast<const bf16x8*>(&tqm[ml * 136 + 16 * c + 8 * hi]);
            bf16x8 bv = ldbf8(wt2b + (32 * dt + ml) * 256 + 16 * c + 8 * hi);
            g = MFMA32(av, bv, g);
        }
#pragma unroll
        for (int c = 8; c < 16; ++c) {  // k >= 128: query from global
            const float* p = query + (n0 + ml) * DD + 16 * (c - 8) + 8 * hi;
            float4 x0 = reinterpret_cast<const float4*>(p)[0];
            float4 x1 = reinterpret_cast<const float4*>(p)[1];
            AW av;
            av.u[0] = pk2(x0.x, x0.y); av.u[1] = pk2(x0.z, x0.w);
            av.u[2] = pk2(x1.x, x1.y); av.u[3] = pk2(x1.z, x1.w);
            bf16x8 bv = ldbf8(wt2b + (32 * dt + ml) * 256 + 16 * c + 8 * hi);
            g = MFMA32(av.v, bv, g);
        }
        const float TWO_L2E = 2.88539008177792681472f;  // 2*log2(e)
        const int d = 32 * dt + ml;
        const float bias = bt2[d];
#pragma unroll
        for (int r = 0; r < 16; ++r) {
            int row = (r & 3) + 8 * (r >> 2) + 4 * hi;
            float x = g[r] + bias;
            float gt = 1.0f - 2.0f / (__builtin_amdgcn_exp2f(x * TWO_L2E) + 1.0f);
            float qv = query[(n0 + row) * DD + d];
            float mv = bfl((unsigned)tqm[row * 136 + d] << 0) , mv2;
            // bf16 -> f32 (value stored as raw bf16 bits)
            union { unsigned v; float f; } cu; cu.v = ((unsigned)tqm[row * 136 + d]) << 16;
            mv = cu.f; (void)mv2;
            out[(n0 + row) * DD + d] = qv + gt * (mv - qv);
        }
    }
}

// ---------------------------------------------------------------------------
extern "C" void kernel_launch(void* const* d_in, const int* in_sizes, int n_in,
                              void* d_out, int out_size, void* d_ws, size_t ws_size,
                              hipStream_t stream) {
    const float* query = (const float*)d_in[0];   // [N,128]
    const float* wt    = (const float*)d_in[1];   // [128,128]
    const float* bt    = (const float*)d_in[2];   // [128]
    const float* miw   = (const float*)d_in[3];   // [M,128]
    const float* mw    = (const float*)d_in[4];   // [M,128]
    const float* wt2   = (const float*)d_in[5];   // [128,256]
    const float* bt2   = (const float*)d_in[6];   // [128]

    float* out    = (float*)d_out;                // output 0: [N,128]
    float* me_out = out + (size_t)NQ * DD;        // output 1: mem_emb [N,128]

    // workspace layout (bf16 arrays), ~1.2 MB total
    unsigned short* minn = (unsigned short*)d_ws;          // [M][128]
    unsigned short* mwt  = minn + (size_t)MM * DD;         // [128][M]
    unsigned short* wtb  = mwt + (size_t)DD * MM;          // [128][128]
    unsigned short* wt2b = wtb + (size_t)DD * DD;          // [128][256]

    k01_prep<<<256, 256, 0, stream>>>(miw, mw, wt, wt2, minn, mwt, wtb, wt2b);
    k3_fused<<<NQ / 32, 256, 0, stream>>>(query, wtb, bt, minn, mwt, wt2b, bt2,
                                          me_out, out);
}

// Round 6
// 66.877 us; speedup vs baseline: 3.2498x; 1.0313x over previous
//
#include <hip/hip_runtime.h>
#include <hip/hip_bf16.h>

#define NQ 16384
#define MM 2048
#define DD 128

typedef __attribute__((ext_vector_type(8))) short bf16x8;
typedef __attribute__((ext_vector_type(4))) float f32x4;
typedef __attribute__((ext_vector_type(16))) float f32x16;

#define MFMA16(a, b, c) __builtin_amdgcn_mfma_f32_16x16x32_bf16((a), (b), (c), 0, 0, 0)
#define MFMA32(a, b, c) __builtin_amdgcn_mfma_f32_32x32x16_bf16((a), (b), (c), 0, 0, 0)

static __device__ __forceinline__ unsigned short f2bf(float x) {
    union { __hip_bfloat16 h; unsigned short u; } cv;
    cv.h = __float2bfloat16(x);
    return cv.u;
}
static __device__ __forceinline__ unsigned pk2(float a, float b) {
    return (unsigned)f2bf(a) | ((unsigned)f2bf(b) << 16);
}
static __device__ __forceinline__ float bfl(unsigned u) {
    union { unsigned v; float f; } c; c.v = u << 16; return c.f;
}
static __device__ __forceinline__ float bfh(unsigned u) {
    union { unsigned v; float f; } c; c.v = u & 0xffff0000u; return c.f;
}
static __device__ __forceinline__ bf16x8 ldbf8(const unsigned short* p) {
    return *reinterpret_cast<const bf16x8*>(p);
}

union AW { unsigned u[4]; bf16x8 v; };

// ---------------------------------------------------------------------------
// K01: merged prep. blocks 0..31: normalize memory_index_w -> minn bf16 and
// transpose memory_w -> mwt bf16 [D][M], two m-rows per thread (4B stores).
// blocks 32..79: convert W_t / W_t2 -> bf16, float4-vectorized.
// ---------------------------------------------------------------------------
__global__ __launch_bounds__(256) void k01_prep(const float* __restrict__ miw,
                                                const float* __restrict__ mw,
                                                const float* __restrict__ wt,
                                                const float* __restrict__ wt2,
                                                unsigned short* __restrict__ minn,
                                                unsigned short* __restrict__ mwt,
                                                unsigned short* __restrict__ wtb,
                                                unsigned short* __restrict__ wt2b) {
    int b = blockIdx.x;
    if (b >= 32) {
        int i = (b - 32) * 1024 + threadIdx.x * 4;   // 48 blocks cover 49152
        if (i < DD * DD) {
            float4 x = *reinterpret_cast<const float4*>(wt + i);
            uint2 u = make_uint2(pk2(x.x, x.y), pk2(x.z, x.w));
            *reinterpret_cast<uint2*>(wtb + i) = u;
        } else {
            int j = i - DD * DD;
            float4 x = *reinterpret_cast<const float4*>(wt2 + j);
            uint2 u = make_uint2(pk2(x.x, x.y), pk2(x.z, x.w));
            *reinterpret_cast<uint2*>(wt2b + j) = u;
        }
        return;
    }
    int t = threadIdx.x;
    int pr = t >> 3;             // row-pair index 0..31
    int e = t & 7;               // column eighth (16 cols)
    int m0 = b * 64 + pr * 2;    // even m row

    // --- memory_index_w: two rows, normalize each ---
    float v0[16], v1[16];
    float ss0 = 0.f, ss1 = 0.f;
#pragma unroll
    for (int k = 0; k < 4; ++k) {
        float4 x = reinterpret_cast<const float4*>(miw + m0 * DD + e * 16)[k];
        v0[4 * k] = x.x; v0[4 * k + 1] = x.y; v0[4 * k + 2] = x.z; v0[4 * k + 3] = x.w;
        ss0 += x.x * x.x + x.y * x.y + x.z * x.z + x.w * x.w;
        float4 y = reinterpret_cast<const float4*>(miw + (m0 + 1) * DD + e * 16)[k];
        v1[4 * k] = y.x; v1[4 * k + 1] = y.y; v1[4 * k + 2] = y.z; v1[4 * k + 3] = y.w;
        ss1 += y.x * y.x + y.y * y.y + y.z * y.z + y.w * y.w;
    }
    ss0 += __shfl_xor(ss0, 1); ss0 += __shfl_xor(ss0, 2); ss0 += __shfl_xor(ss0, 4);
    ss1 += __shfl_xor(ss1, 1); ss1 += __shfl_xor(ss1, 2); ss1 += __shfl_xor(ss1, 4);
    float sc0 = 1.0f / fmaxf(sqrtf(ss0), 1e-8f);
    float sc1 = 1.0f / fmaxf(sqrtf(ss1), 1e-8f);

    unsigned* d0 = reinterpret_cast<unsigned*>(minn + m0 * DD + e * 16);
    unsigned* d1 = reinterpret_cast<unsigned*>(minn + (m0 + 1) * DD + e * 16);
#pragma unroll
    for (int k = 0; k < 8; ++k) {
        d0[k] = pk2(v0[2 * k] * sc0, v0[2 * k + 1] * sc0);
        d1[k] = pk2(v1[2 * k] * sc1, v1[2 * k + 1] * sc1);
    }

    // --- memory_w transpose: two rows -> 4B stores ---
    float w0[16], w1[16];
#pragma unroll
    for (int k = 0; k < 4; ++k) {
        float4 x = reinterpret_cast<const float4*>(mw + m0 * DD + e * 16)[k];
        w0[4 * k] = x.x; w0[4 * k + 1] = x.y; w0[4 * k + 2] = x.z; w0[4 * k + 3] = x.w;
        float4 y = reinterpret_cast<const float4*>(mw + (m0 + 1) * DD + e * 16)[k];
        w1[4 * k] = y.x; w1[4 * k + 1] = y.y; w1[4 * k + 2] = y.z; w1[4 * k + 3] = y.w;
    }
#pragma unroll
    for (int k = 0; k < 16; ++k)
        *reinterpret_cast<unsigned*>(mwt + (e * 16 + k) * MM + m0) = pk2(w0[k], w1[k]);
}

// ---------------------------------------------------------------------------
// K3: fully fused transform + attention + gating.  BARRIER-FREE main loop.
// Grid 512 x 256thr. Block = one 32-query strip; wave w = m-quarter
// [512w, 512w+512), 16 iters of 32 m.  Each wave stages ITS OWN 8 KB minn
// tile (32 rows, source-swizzled) into ITS OWN double-buffered LDS segment
// via global_load_lds; per-wave counted vmcnt only — no s_barrier in loop.
// Epilogue: bf16 LDS reduction across waves, then fused gating GEMM.
// ---------------------------------------------------------------------------
__global__ __launch_bounds__(256, 2) void k3_fused(const float* __restrict__ query,
                                                   const unsigned short* __restrict__ wtb,
                                                   const float* __restrict__ bt,
                                                   const unsigned short* __restrict__ minn,
                                                   const unsigned short* __restrict__ mwt,
                                                   const unsigned short* __restrict__ wt2b,
                                                   const float* __restrict__ bt2,
                                                   float* __restrict__ me_out,
                                                   float* __restrict__ out) {
    // [0,65536): per-wave staging, wave w at w*16384 (+8192 for buf1).
    //            epilogue: reduction slots (aliased, post-loop-barrier).
    // [65536,74240): tq / me tile, 32 rows x 136 shorts.
    __shared__ __align__(16) char pool[74240];
    unsigned short* tqm = reinterpret_cast<unsigned short*>(pool + 65536);

    const int lane = threadIdx.x & 63;
    const int wid = threadIdx.x >> 6;   // m-quarter
    const int ml = lane & 31;
    const int hi = lane >> 5;
    const int n0 = blockIdx.x * 32;
    const float L2E = 1.44269504088896340736f;

    char* wbuf = pool + wid * 16384;
    const int mq = wid * 512;

    // stage a 32-row (8 KB) minn tile into this wave's buffer.
    // LDS dest linear (base + lane*16); global source column XOR-swizzled by
    // (row&15)<<4 so the swizzled ds_read_b128 below is conflict-free.
    auto stage = [&](int m0, char* buf) {
#pragma unroll
        for (int k = 0; k < 8; ++k) {
            int row = k * 4 + (lane >> 4);            // 0..31
            int scol = ((lane & 15) * 16) ^ ((row & 15) << 4);
            const unsigned short* src = minn + (m0 + row) * DD + scol / 2;
            __builtin_amdgcn_global_load_lds(
                (const __attribute__((address_space(1))) unsigned int*)src,
                (__attribute__((address_space(3))) unsigned int*)(buf + k * 1024),
                16, 0, 0);
        }
    };

    // prologue: start DMA of this wave's tile 0
    stage(mq, wbuf);

    // ---- Phase 0: transform 32 q (waves 0,1; 16x16 path), tq pre-scaled L2E
    if (wid < 2) {
        const int nl = lane & 15;
        const int g = lane >> 4;
        const int qb = n0 + 16 * wid;
        AW aq[4];
#pragma unroll
        for (int c = 0; c < 4; ++c) {
            const float* p = query + (qb + nl) * DD + 32 * c + 8 * g;
            float4 x0 = reinterpret_cast<const float4*>(p)[0];
            float4 x1 = reinterpret_cast<const float4*>(p)[1];
            aq[c].u[0] = pk2(x0.x, x0.y); aq[c].u[1] = pk2(x0.z, x0.w);
            aq[c].u[2] = pk2(x1.x, x1.y); aq[c].u[3] = pk2(x1.z, x1.w);
        }
        f32x4 acc[8];
#pragma unroll
        for (int t = 0; t < 8; ++t) acc[t] = (f32x4){0.f, 0.f, 0.f, 0.f};
#pragma unroll
        for (int t = 0; t < 8; ++t)
#pragma unroll
            for (int c = 0; c < 4; ++c) {
                bf16x8 bv = ldbf8(wtb + (16 * t + nl) * DD + 32 * c + 8 * g);
                acc[t] = MFMA16(aq[c].v, bv, acc[t]);
            }
        float ss[4] = {0.f, 0.f, 0.f, 0.f};
#pragma unroll
        for (int t = 0; t < 8; ++t) {
            float bias = bt[16 * t + nl];
#pragma unroll
            for (int r = 0; r < 4; ++r) {
                float v = acc[t][r] + bias;
                acc[t][r] = v;
                ss[r] += v * v;
            }
        }
#pragma unroll
        for (int r = 0; r < 4; ++r) {
            ss[r] += __shfl_xor(ss[r], 1);
            ss[r] += __shfl_xor(ss[r], 2);
            ss[r] += __shfl_xor(ss[r], 4);
            ss[r] += __shfl_xor(ss[r], 8);
        }
        float scl[4];
#pragma unroll
        for (int r = 0; r < 4; ++r) scl[r] = L2E / fmaxf(sqrtf(ss[r]), 1e-8f);
#pragma unroll
        for (int t = 0; t < 8; ++t)
#pragma unroll
            for (int r = 0; r < 4; ++r)
                tqm[(16 * wid + 4 * g + r) * 136 + 16 * t + nl] = f2bf(acc[t][r] * scl[r]);
    }
    __syncthreads();  // tq visible to all waves

    // Qn B-fragments (col n = ml, k = d)
    bf16x8 qn[8];
#pragma unroll
    for (int c = 0; c < 8; ++c)
        qn[c] = *reinterpret_cast<const bf16x8*>(&tqm[ml * 136 + 16 * c + 8 * hi]);

    const f32x16 zero16 = {0.f,0.f,0.f,0.f,0.f,0.f,0.f,0.f,0.f,0.f,0.f,0.f,0.f,0.f,0.f,0.f};
    f32x16 o[4];
#pragma unroll
    for (int t = 0; t < 4; ++t) o[t] = zero16;
    float den = 0.0f;

#pragma unroll 2
    for (int it = 0; it < 16; ++it) {
        // issue next tile's DMA into the other buffer (wave-private)
        if (it < 15) stage(mq + (it + 1) * 32, wbuf + (((it + 1) & 1) ? 8192 : 0));
        // wait for tile `it`: newer ops = stage(it+1)[8] + bw(it-1)[8]
        if (it == 0 || it == 15) {
            asm volatile("s_waitcnt vmcnt(8)" ::: "memory");
        } else {
            asm volatile("s_waitcnt vmcnt(16)" ::: "memory");
        }
        __builtin_amdgcn_sched_barrier(0);

        // QK A-frags from this wave's swizzled LDS tile (row = ml)
        const char* arow = wbuf + ((it & 1) ? 8192 : 0) + ml * 256;
        bf16x8 aA[8];
#pragma unroll
        for (int c = 0; c < 8; ++c)
            aA[c] = *reinterpret_cast<const bf16x8*>(
                arow + ((32 * c + 16 * hi) ^ ((ml & 15) << 4)));

        f32x16 sA = zero16, sB = zero16;
#pragma unroll
        for (int c = 0; c < 4; ++c) sA = MFMA32(aA[c], qn[c], sA);
#pragma unroll
        for (int c = 4; c < 8; ++c) sB = MFMA32(aA[c], qn[c], sB);

        // PV B-frags direct from global mwt[d][m]
        const int m0 = mq + it * 32;
        bf16x8 bw[8];
#pragma unroll
        for (int dt = 0; dt < 4; ++dt)
#pragma unroll
            for (int kc = 0; kc < 2; ++kc)
                bw[dt * 2 + kc] = ldbf8(mwt + (32 * dt + ml) * MM + m0 + 16 * kc + 8 * hi);

        float p[16];
#pragma unroll
        for (int r = 0; r < 16; ++r)
            p[r] = __builtin_amdgcn_exp2f(sA[r] + sB[r]);
        {
            float e0 = (p[0] + p[1]) + (p[2] + p[3]);
            float e1 = (p[4] + p[5]) + (p[6] + p[7]);
            float e2 = (p[8] + p[9]) + (p[10] + p[11]);
            float e3 = (p[12] + p[13]) + (p[14] + p[15]);
            den += (e0 + e1) + (e2 + e3);
        }
        unsigned w0 = pk2(p[0], p[1]),   w1 = pk2(p[2], p[3]);
        unsigned w2 = pk2(p[4], p[5]),   w3 = pk2(p[6], p[7]);
        unsigned w4 = pk2(p[8], p[9]),   w5 = pk2(p[10], p[11]);
        unsigned w6 = pk2(p[12], p[13]), w7 = pk2(p[14], p[15]);
        auto r02 = __builtin_amdgcn_permlane32_swap(w0, w2, false, false);
        auto r13 = __builtin_amdgcn_permlane32_swap(w1, w3, false, false);
        auto r46 = __builtin_amdgcn_permlane32_swap(w4, w6, false, false);
        auto r57 = __builtin_amdgcn_permlane32_swap(w5, w7, false, false);
        AW a0, a1;
        a0.u[0] = r02[0]; a0.u[1] = r13[0]; a0.u[2] = r02[1]; a0.u[3] = r13[1];
        a1.u[0] = r46[0]; a1.u[1] = r57[0]; a1.u[2] = r46[1]; a1.u[3] = r57[1];
#pragma unroll
        for (int dt = 0; dt < 4; ++dt) {
            o[dt] = MFMA32(a0.v, bw[dt * 2 + 0], o[dt]);
            o[dt] = MFMA32(a1.v, bw[dt * 2 + 1], o[dt]);
        }
    }

    // ---- cross-wave reduction (bf16 partials aliased into staging area) ----
    __syncthreads();  // all waves done with their staging buffers
    if (wid >= 1) {
        char* dst = pool + (wid - 1) * 8704 + lane * 136;
#pragma unroll
        for (int t = 0; t < 4; ++t) {
            unsigned u[8];
#pragma unroll
            for (int k = 0; k < 8; ++k) u[k] = pk2(o[t][2 * k], o[t][2 * k + 1]);
            *reinterpret_cast<uint4*>(dst + t * 32) = make_uint4(u[0], u[1], u[2], u[3]);
            *reinterpret_cast<uint4*>(dst + t * 32 + 16) = make_uint4(u[4], u[5], u[6], u[7]);
        }
        *reinterpret_cast<float*>(dst + 128) = den;
    }
    __syncthreads();
    if (wid == 0) {
        for (int s = 0; s < 3; ++s) {
            const char* src = pool + s * 8704 + lane * 136;
#pragma unroll
            for (int t = 0; t < 4; ++t) {
                uint4 ua = *reinterpret_cast<const uint4*>(src + t * 32);
                uint4 ub = *reinterpret_cast<const uint4*>(src + t * 32 + 16);
                unsigned u[8] = {ua.x, ua.y, ua.z, ua.w, ub.x, ub.y, ub.z, ub.w};
#pragma unroll
                for (int k = 0; k < 8; ++k) {
                    o[t][2 * k] += bfl(u[k]);
                    o[t][2 * k + 1] += bfh(u[k]);
                }
            }
            den += *reinterpret_cast<const float*>(src + 128);
        }
        den += __shfl_xor(den, 32);
        float invd = 1.0f / den;
        float inv[16];
#pragma unroll
        for (int r = 0; r < 16; ++r)
            inv[r] = __shfl(invd, (r & 3) + 8 * (r >> 2) + 4 * hi);
#pragma unroll
        for (int t = 0; t < 4; ++t)
#pragma unroll
            for (int r = 0; r < 16; ++r) {
                int row = (r & 3) + 8 * (r >> 2) + 4 * hi;
                float me = o[t][r] * inv[r];
                me_out[(n0 + row) * DD + 32 * t + ml] = me;
                tqm[row * 136 + 32 * t + ml] = f2bf(me);  // me tile for gating
            }
    }
    __syncthreads();

    // ---- fused gating: G = tanh(cat(me,q) @ W_t2^T + b_t2); blend ----
    {
        const int dt = wid;  // d-tile 32*dt .. 32*dt+31
        f32x16 g = zero16;
#pragma unroll
        for (int c = 0; c < 8; ++c) {  // k < 128: me from LDS tile
            bf16x8 av = *reinterpret_cast<const bf16x8*>(&tqm[ml * 136 + 16 * c + 8 * hi]);
            bf16x8 bv = ldbf8(wt2b + (32 * dt + ml) * 256 + 16 * c + 8 * hi);
            g = MFMA32(av, bv, g);
        }
#pragma unroll
        for (int c = 8; c < 16; ++c) {  // k >= 128: query from global
            const float* p = query + (n0 + ml) * DD + 16 * (c - 8) + 8 * hi;
            float4 x0 = reinterpret_cast<const float4*>(p)[0];
            float4 x1 = reinterpret_cast<const float4*>(p)[1];
            AW av;
            av.u[0] = pk2(x0.x, x0.y); av.u[1] = pk2(x0.z, x0.w);
            av.u[2] = pk2(x1.x, x1.y); av.u[3] = pk2(x1.z, x1.w);
            bf16x8 bv = ldbf8(wt2b + (32 * dt + ml) * 256 + 16 * c + 8 * hi);
            g = MFMA32(av.v, bv, g);
        }
        const float TWO_L2E = 2.88539008177792681472f;  // 2*log2(e)
        const int d = 32 * dt + ml;
        const float bias = bt2[d];
#pragma unroll
        for (int r = 0; r < 16; ++r) {
            int row = (r & 3) + 8 * (r >> 2) + 4 * hi;
            float x = g[r] + bias;
            float gt = 1.0f - 2.0f / (__builtin_amdgcn_exp2f(x * TWO_L2E) + 1.0f);
            float qv = query[(n0 + row) * DD + d];
            float mv = bfl(tqm[row * 136 + d]);
            out[(n0 + row) * DD + d] = qv + gt * (mv - qv);
        }
    }
}

// ---------------------------------------------------------------------------
extern "C" void kernel_launch(void* const* d_in, const int* in_sizes, int n_in,
                              void* d_out, int out_size, void* d_ws, size_t ws_size,
                              hipStream_t stream) {
    const float* query = (const float*)d_in[0];   // [N,128]
    const float* wt    = (const float*)d_in[1];   // [128,128]
    const float* bt    = (const float*)d_in[2];   // [128]
    const float* miw   = (const float*)d_in[3];   // [M,128]
    const float* mw    = (const float*)d_in[4];   // [M,128]
    const float* wt2   = (const float*)d_in[5];   // [128,256]
    const float* bt2   = (const float*)d_in[6];   // [128]

    float* out    = (float*)d_out;                // output 0: [N,128]
    float* me_out = out + (size_t)NQ * DD;        // output 1: mem_emb [N,128]

    // workspace layout (bf16 arrays), ~1.2 MB total
    unsigned short* minn = (unsigned short*)d_ws;          // [M][128]
    unsigned short* mwt  = minn + (size_t)MM * DD;         // [128][M]
    unsigned short* wtb  = mwt + (size_t)DD * MM;          // [128][128]
    unsigned short* wt2b = wtb + (size_t)DD * DD;          // [128][256]

    k01_prep<<<80, 256, 0, stream>>>(miw, mw, wt, wt2, minn, mwt, wtb, wt2b);
    k3_fused<<<NQ / 32, 256, 0, stream>>>(query, wtb, bt, minn, mwt, wt2b, bt2,
                                          me_out, out);
}